// Round 12
// baseline (1645.481 us; speedup 1.0000x reference)
//
#include <hip/hip_runtime.h>
#include <hip/hip_bf16.h>
#include <cmath>

// RecursiveQuantumTransformerLayer on MI355X (gfx950).
// B=4, S=1024, E=1024, H=16, D=64, F=4096, DEPTH=3.
// [Round 19:
//  - gemm_bt: BK=32 double-buffered (32KB LDS -> 4 blocks/CU = 32 waves,
//    full wave cap; was 2 blocks at BK=64/64KB). Swizzle slot=lq^((row>>1)&3)
//    (2-way bank = free); one barrier per K-step; same ascending-32 K order
//    -> bit-identical.
//  - flash: reverted to non-KV-split 16-kt direct-output kernel (R15).
//    KV-split was net-negative: 75+11(flashc)+48MB traffic vs 81 direct.
//  All other Round-18 structure kept.]

typedef unsigned short u16;
typedef short v8s __attribute__((ext_vector_type(8)));
typedef float v4f __attribute__((ext_vector_type(4)));
typedef unsigned short u16x4 __attribute__((ext_vector_type(4)));
typedef unsigned int u32x4 __attribute__((ext_vector_type(4)));

#define DEV __device__ __forceinline__

DEV float b2f(u16 u) { return __uint_as_float(((unsigned int)u) << 16); }
DEV u16 f2b(float f) {
    unsigned int x = __float_as_uint(f);
    return (u16)((x + 0x7fffu + ((x >> 16) & 1u)) >> 16);  // RNE
}
DEV bool badf(float f) { return ((__float_as_uint(f) >> 23) & 0xFF) == 0xFF; }

DEV void async16(const void* g, void* l) {
    __builtin_amdgcn_global_load_lds((const __attribute__((address_space(1))) void*)g,
                                     (__attribute__((address_space(3))) void*)l, 16, 0, 0);
}

struct InArr { const void* p[37]; int n[37]; };
struct BJobs { int si[20]; int off[20]; int n[20]; };
struct GJ2 { const u16* jA; const u16* jB; const u16* jbias; u16* jout; };

#define CLS_CAP 16384  // pairs sampled per input (64 KB), 8 chunks x 2048

// ---------------- setup / diagnostics ----------------
__global__ void reset_k(int* diag, int* cnt) {
    if (threadIdx.x == 0) *diag = 0x7FFFFFFF;
    if (threadIdx.x < 80) cnt[threadIdx.x] = 0;
}

__global__ void classify_k(InArr A, int* cnt) {
    int i = blockIdx.y;
    int n = A.n[i];
    if (n <= 1) return;
    long pairs = (long)n >> 1;
    int wild = 0, pz = 0;
    if (pairs > (long)(2 * CLS_CAP)) {
        // Sampled: 8 evenly spaced chunks of 2048 pairs, u32x4 vector loads.
        const unsigned int* q32 = (const unsigned int*)A.p[i];
        long p0 = ((long)blockIdx.x * (pairs >> 3)) & ~3L;
        long tbase = p0 + (long)threadIdx.x * 8;
#pragma unroll
        for (int c = 0; c < 2; c++) {
            u32x4 v = *(const u32x4*)(q32 + tbase + c * 4);
#pragma unroll
            for (int j = 0; j < 4; j++) {
                unsigned int p = v[j];
                u16 w0 = (u16)(p & 0xFFFFu), w1 = (u16)(p >> 16);
                wild += ((w0 & 0x7FFF) >= 0x5000) + ((w1 & 0x7FFF) >= 0x5000);
                pz += (w0 == 0 && w1 >= 0x3000 && w1 <= 0x4100) ? 1 : 0;
            }
        }
    } else {
        const u16* q = (const u16*)A.p[i];
        long stride = (long)gridDim.x * blockDim.x;
        for (long j = (long)blockIdx.x * blockDim.x + threadIdx.x; j < pairs; j += stride) {
            u16 w0 = q[2 * j], w1 = q[2 * j + 1];
            wild += ((w0 & 0x7FFF) >= 0x5000) + ((w1 & 0x7FFF) >= 0x5000);
            pz += (w0 == 0 && w1 >= 0x3000 && w1 <= 0x4100) ? 1 : 0;
        }
    }
#pragma unroll
    for (int off = 1; off < 64; off <<= 1) {
        wild += __shfl_xor(wild, off);
        pz += __shfl_xor(pz, off);
    }
    if ((threadIdx.x & 63) == 0) {
        atomicAdd(&cnt[2 * i], wild);
        atomicAdd(&cnt[2 * i + 1], pz);
    }
}

__global__ void finalize_k(InArr A, const int* cnt, int* flags) {
    int i = threadIdx.x;
    if (i < 37) {
        int n = A.n[i];
        int f = 0;
        if (n > 1) {
            long pairs = (long)n >> 1;
            long wthr, pthr;
            if (pairs > (long)(2 * CLS_CAP)) { wthr = (2L * CLS_CAP) >> 6; pthr = (long)CLS_CAP >> 2; }
            else { wthr = (long)n >> 6; pthr = (long)n >> 3; }
            f = (cnt[2 * i] > wthr) || (cnt[2 * i + 1] > pthr);
        }
        flags[i] = f;
    }
}

DEV float dec_scalar(const u16* p) {
    float bf = b2f(p[0]);
    if (bf > 0.0009765625f && bf < 8.0f) return bf;
    unsigned int w = (((unsigned int)p[1]) << 16) | (unsigned int)p[0];
    return __uint_as_float(w);
}

__global__ void decode_scalars_k(const u16* rg, const u16* tp, const u16* et,
                                 const u16* og, float* out)
{
    if (threadIdx.x == 0 && blockIdx.x == 0) {
        out[0] = dec_scalar(rg);
        out[1] = dec_scalar(tp);
        out[2] = dec_scalar(et);
        out[3] = dec_scalar(og);
    }
}

__global__ void cvt1d_k(InArr A, BJobs J, const int* flags, u16* BIA) {
    int j = blockIdx.y;
    int n = J.n[j];
    int si = J.si[j];
    const void* src = A.p[si];
    u16* dst = BIA + (long)J.off[j] * 1024;
    int f = flags[si];
    int stride = gridDim.x * blockDim.x;
    for (int i = blockIdx.x * blockDim.x + threadIdx.x; i < n; i += stride) {
        dst[i] = f ? f2b(((const float*)src)[i]) : ((const u16*)src)[i];
    }
}

__global__ void chk_scal_k(const float* scal, int* diag) {
    if (threadIdx.x == 0) {
        for (int i = 0; i < 4; i++) {
            float v = scal[i];
            if (!(v > 0.f && v < 8.f)) atomicMin(diag, 3);
        }
    }
}

// Sanitize fp32 outputs; if a stage fired, encode it at out[0] (fp32).
__global__ void fin32_k(float* out, long n4, const int* diag) {
    long stride = (long)gridDim.x * blockDim.x;
    long i0 = (long)blockIdx.x * blockDim.x + threadIdx.x;
    v4f* o4 = (v4f*)out;
    for (long i = i0; i < n4; i += stride) {
        v4f v = o4[i];
        bool b = false;
#pragma unroll
        for (int j = 0; j < 4; j++) b |= badf(v[j]);
        if (b) {
#pragma unroll
            for (int j = 0; j < 4; j++) if (badf(v[j])) v[j] = 0.f;
            o4[i] = v;
        }
    }
    if (i0 == 0) {
        int d = *diag;
        if (d != 0x7FFFFFFF) out[0] = 200.f + 4.f * (float)(d < 70 ? d : 70);
    }
}

__global__ void small_k(float* out, int code) {
    if (threadIdx.x == 0 && blockIdx.x == 0) out[0] = 900.f + 4.f * code;
}

// f2 split-K combine: out = bf16(a + b + bias), fused NaN check.
__global__ __launch_bounds__(256) void f2c_k(const float* __restrict__ a, const float* __restrict__ b,
                                             const u16* __restrict__ bias, u16* __restrict__ out,
                                             int stage, int* __restrict__ diag)
{
    long i0 = ((long)blockIdx.x * 256 + threadIdx.x) * 4;
    v4f va = *(const v4f*)(a + i0);
    v4f vb = *(const v4f*)(b + i0);
    int colb = (int)(i0 & 1023);
    bool bad = false;
    u16x4 o;
#pragma unroll
    for (int j = 0; j < 4; j++) {
        float r = va[j] + vb[j] + b2f(bias[colb + j]);
        bad |= badf(r);
        o[j] = f2b(r);
    }
    *(u16x4*)(out + i0) = o;
    if (__ballot(bad) && (threadIdx.x & 63) == 0) atomicMin(diag, stage);
}

// ig split-K combine: gate = sigmoid(a + b + bias), fused NaN check.
__global__ __launch_bounds__(256) void igc_k(const float* __restrict__ a, const float* __restrict__ b,
                                             const u16* __restrict__ bias, u16* __restrict__ out,
                                             int stage, int* __restrict__ diag)
{
    long i0 = ((long)blockIdx.x * 256 + threadIdx.x) * 4;
    v4f va = *(const v4f*)(a + i0);
    v4f vb = *(const v4f*)(b + i0);
    int colb = (int)(i0 & 1023);
    bool bad = false;
    u16x4 o;
#pragma unroll
    for (int j = 0; j < 4; j++) {
        float r = 1.f / (1.f + expf(-(va[j] + vb[j] + b2f(bias[colb + j]))));
        bad |= badf(r);
        o[j] = f2b(r);
    }
    *(u16x4*)(out + i0) = o;
    if (__ballot(bad) && (threadIdx.x & 63) == 0) atomicMin(diag, stage);
}

// ---------------------------------------------------------------------------
// GEMM: C[M,N] = A[M,K] * Bt[N,K]^T (+bias) with fused epilogues.
// 128x128 tile, BK=32, DOUBLE-BUFFERED LDS (32KB -> 4 blocks/CU = 32 waves,
// full wave cap). Swizzle slot = lq ^ ((row>>1)&3): 2-way bank (free).
// Next tile's async16 issued before current ds_read+MFMA; ONE barrier/step.
// 512 threads (8 waves 2Mx4N, each 64x32 = 4x2 mfma 16x16x32).
// XCD-chunked block swizzle. Ascending-32 K order -> bit-identical.
// EPI: 0=bias, 2=GELU, 5=OBS,
//      6=dual-out (col<1024: SR residual -> obf; col>=1024 -> J2.jout),
//      7=dual-out plain, col<1024 scaled by 0.125 (q for flash; exact 2^-3),
//      8=fp32 partial (no bias; split-K; dual-job -> (float*)J2.jout).
// J2.jA != null => dual-job: z >= gridDim.z/2 switches {A,Bt,bias,out}.
// Output NaN/Inf check fused (ballot+atomicMin(diag,stage)).
// ---------------------------------------------------------------------------
template <int EPI>
__global__ __launch_bounds__(512) void gemm_bt(
    const u16* __restrict__ A, int lda, long sA,
    const u16* __restrict__ A2, int ksplit,
    const u16* __restrict__ Bt, int ldb, long sB,
    const u16* __restrict__ bias,
    u16* __restrict__ obf, float* __restrict__ of32, int ldc, long sC,
    int K,
    const float* __restrict__ scp,
    const u16* __restrict__ aux,
    float* __restrict__ xaux, float* __restrict__ ksf, u16* __restrict__ ksb,
    float* __restrict__ kso,
    GJ2 J2,
    int stage, int* __restrict__ diag)
{
    __shared__ __align__(16) u16 As[2 * 128 * 32];
    __shared__ __align__(16) u16 Bs[2 * 128 * 32];
    const int tid = threadIdx.x;
    const int w = tid >> 6, l = tid & 63;
    const int lr = l & 15, lq = l >> 4;

    // Bijective XCD-chunked swizzle over the whole grid (x-major flat id).
    const int gx = gridDim.x, gy = gridDim.y;
    const int nwg = gx * gy * (int)gridDim.z;
    int flat = blockIdx.x + gx * (blockIdx.y + gy * blockIdx.z);
    int qq = nwg >> 3, rr = nwg & 7;
    int xcd = flat & 7, loc = flat >> 3;
    int nf = (xcd < rr ? xcd * (qq + 1) : rr * (qq + 1) + (xcd - rr) * qq) + loc;
    const int bx = nf % gx;
    int tmp = nf / gx;
    const int by = tmp % gy;
    int z = tmp / gy;

    // Dual-job pointer switch (upper half of z selects job B).
    const u16* Aj = A; const u16* Bj = Bt; const u16* biasj = bias; u16* obfj = obf;
    float* of32j = of32;
    if (J2.jA) {
        int jzs = (int)gridDim.z >> 1;
        if (z >= jzs) {
            Aj = J2.jA; Bj = J2.jB; biasj = J2.jbias;
            if (EPI == 8) of32j = (float*)J2.jout; else obfj = J2.jout;
            z -= jzs;
        }
    }

    const int m0 = by * 128, n0 = bx * 128;
    const u16* Az = Aj + (long)z * sA;
    const u16* Bz = Bj + (long)z * sB;
    const int wm = (w >> 2) * 64, wn = (w & 3) * 32;

    v4f zero4 = {0.f, 0.f, 0.f, 0.f};
    v4f acc[4][2];
#pragma unroll
    for (int i = 0; i < 4; i++)
#pragma unroll
        for (int j = 0; j < 2; j++) acc[i][j] = zero4;

    // Read slot: row bits 1-2 come from lr (row = mult16 + lr).
    const int cslot = (lq ^ ((lr >> 1) & 3)) << 3;   // u16 units in 32-u16 row
    // Staging constants: one async16 pair per thread per K-step.
    const int srow = tid >> 2;                       // 0..127
    const int ssc = (((tid & 3) ^ ((srow >> 1) & 3)) * 8);  // inverse-swizzled src col

    // Prologue: stage k0=0 into buffer 0.
    {
        const u16* Ab = (0 < ksplit) ? Az : A2;
        async16(Ab + (long)(m0 + srow) * lda + ssc, (char*)As + w * 1024);
        async16(Bz + (long)(n0 + srow) * ldb + ssc, (char*)Bs + w * 1024);
    }
    __syncthreads();
    int cur = 0;
    for (int k0 = 0; k0 < K; k0 += 32) {
        int kn = k0 + 32;
        if (kn < K) {
            const u16* Ab = (kn < ksplit) ? (Az + kn) : (A2 + (kn - ksplit));
            int nb = (cur ^ 1) * 8192;   // bytes per buffer
            async16(Ab + (long)(m0 + srow) * lda + ssc, (char*)As + nb + w * 1024);
            async16(Bz + (long)(n0 + srow) * ldb + kn + ssc, (char*)Bs + nb + w * 1024);
        }
        const u16* Asc = As + cur * 4096;   // u16 units per buffer
        const u16* Bsc = Bs + cur * 4096;
        v8s av[4], bv[2];
#pragma unroll
        for (int mi = 0; mi < 4; mi++)
            av[mi] = *(const v8s*)(Asc + ((wm + mi * 16 + lr) << 5) + cslot);
#pragma unroll
        for (int ni = 0; ni < 2; ni++)
            bv[ni] = *(const v8s*)(Bsc + ((wn + ni * 16 + lr) << 5) + cslot);
#pragma unroll
        for (int mi = 0; mi < 4; mi++)
#pragma unroll
            for (int ni = 0; ni < 2; ni++)
                acc[mi][ni] = __builtin_amdgcn_mfma_f32_16x16x32_bf16(av[mi], bv[ni], acc[mi][ni], 0, 0, 0);
        __syncthreads();   // drains prefetch; frees cur for next overwrite
        cur ^= 1;
    }

    float gsv = 0.f;
    if (EPI == 5 || EPI == 6) gsv = scp[0];
    bool bad = false;
#pragma unroll
    for (int mi = 0; mi < 4; mi++) {
        int row = m0 + wm + mi * 16 + lq * 4;
#pragma unroll
        for (int ni = 0; ni < 2; ni++) {
            int col = n0 + wn + ni * 16 + lr;
            float bb = biasj ? b2f(biasj[col]) : 0.f;
#pragma unroll
            for (int r = 0; r < 4; r++) {
                float v = acc[mi][ni][r] + bb;
                if (EPI == 6 || EPI == 7) {
                    long rbase = (long)(row + r) * 1024;
                    float res;
                    if (col < 1024) {
                        if (EPI == 6) res = b2f(aux[rbase + col]) + gsv * v;
                        else res = v * 0.125f;   // q pre-scale (exact 2^-3)
                        bad |= badf(res);
                        obfj[rbase + col] = f2b(res);
                    } else {
                        res = v;
                        bad |= badf(res);
                        J2.jout[rbase + col - 1024] = f2b(res);
                    }
                } else {
                    long idx = (long)z * sC + (long)(row + r) * ldc + col;
                    float res = v;
                    if (EPI == 2) res = 0.5f * v * (1.f + erff(v * 0.70710678118654752f));
                    else if (EPI == 5) {
                        float xv = xaux[idx];
                        float nx = xv + gsv * v;
                        xaux[idx] = nx;
                        float kv = ksf[idx];
                        float kn = kv + 0.1f * (nx - kv);
                        ksf[idx] = kn;
                        ksb[idx] = f2b(kn);
                        if (kso) kso[idx] = kn;
                        bad |= badf(kn);
                        res = nx;
                    }
                    bad |= badf(res);
                    if (obfj) obfj[idx] = f2b(res);
                    if (of32j) of32j[idx] = res;
                }
            }
        }
    }
    if (__ballot(bad) && l == 0) atomicMin(diag, stage);
}

// ---------------------------------------------------------------------------
// Flash attention: grid (16 qtiles, 64 bh). 4 waves x 16 q-rows. D=64.
// Non-split (direct bf16 output): KV-split partial round-trip was net
// negative. XCD-locality remap: each XCD owns 8 complete (b,h) groups.
// Ks double-buffered; K/V prefetch at loop top; Vt swizzle precomputed;
// q arrives pre-scaled by 0.125.
// ---------------------------------------------------------------------------
__global__ __launch_bounds__(256) void flash_k(
    const u16* __restrict__ q, const u16* __restrict__ k, const u16* __restrict__ v,
    u16* __restrict__ ao, int stage, int* __restrict__ diag)
{
    __shared__ __align__(16) u16 Ks[2 * 64 * 64];
    __shared__ __align__(16) u16 Vt[64 * 64];
    __shared__ __align__(16) u16 Pw[4 * 16 * 64];
    const int tid = threadIdx.x, w = tid >> 6, l = tid & 63;
    const int lr = l & 15, lq = l >> 4;
    // XCD-locality remap (grid is (16, 64), 1024 blocks, bijective).
    const int flat = blockIdx.x + (blockIdx.y << 4);
    const int xcd = flat & 7, loc = flat >> 3;      // loc 0..127
    const int bh = xcd * 8 + (loc >> 4);            // 8 bh per XCD
    const int q0 = (loc & 15) * 64;
    const int b = bh >> 4, h = bh & 15;
    const long rowbase = (long)b * 1024;
    const int h64 = h * 64;

    const u16* Qp = q + (rowbase + q0 + w * 16 + lr) * 1024 + h64;
    v8s aq0 = *(const v8s*)(Qp + lq * 8);
    v8s aq1 = *(const v8s*)(Qp + 32 + lq * 8);

    v4f zero4 = {0.f, 0.f, 0.f, 0.f};
    v4f oacc[4];
    float m_r[4], l_r[4];
#pragma unroll
    for (int i = 0; i < 4; i++) { oacc[i] = zero4; m_r[i] = -INFINITY; l_r[i] = 0.f; }

    const int ss = lr & 7;                 // row-swizzle bits for Ks/Pw reads
    const int colk = (lq ^ ss) << 3;       // swizzled column byte-slot (u16 units)
    u16* Pp = Pw + w * (16 * 64);

    // Staging constants (fixed per thread).
    const int c0 = tid, c1 = 256 + tid;
    const int row0 = c0 >> 3, cc0 = (c0 & 7) * 8;
    const int row1 = c1 >> 3, cc1 = (c1 & 7) * 8;
    const int sl0 = ((c0 & 7) ^ (row0 & 7)) * 8;
    const int sl1 = ((c1 & 7) ^ (row1 & 7)) * 8;
    int vt0[8], vt1[8];
#pragma unroll
    for (int j = 0; j < 8; j++) {
        int d0 = cc0 + j, g0 = (d0 & 7) ^ ((d0 >> 3) & 7);
        vt0[j] = ((d0 << 6) + row0) ^ (g0 << 3);
        int d1 = cc1 + j, g1 = (d1 & 7) ^ ((d1 >> 3) & 7);
        vt1[j] = ((d1 << 6) + row1) ^ (g1 << 3);
    }
    const u16* kc0 = k + (rowbase + row0) * 1024 + h64 + sl0;
    const u16* kc1 = k + (rowbase + row1) * 1024 + h64 + sl1;
    const u16* vc0 = v + (rowbase + row0) * 1024 + h64 + cc0;
    const u16* vc1 = v + (rowbase + row1) * 1024 + h64 + cc1;

    // Prologue: stage kt=0.
    async16(kc0, (char*)Ks + w * 1024);
    async16(kc1, (char*)Ks + 4096 + w * 1024);
    v8s vv0 = *(const v8s*)vc0;
    v8s vv1 = *(const v8s*)vc1;
    v8s vvn0 = vv0, vvn1 = vv1;
    int cur = 0;

    for (int kt = 0; kt < 16; kt++) {
        __syncthreads();   // prev PV done (Vt free); K(kt)/V(kt) drained
        const long koff = (long)(kt + 1) << 16;   // (kt+1)*64 rows * 1024
        if (kt < 15) {
            int nb = (cur ^ 1) * 8192;
            async16(kc0 + koff, (char*)Ks + nb + w * 1024);
            async16(kc1 + koff, (char*)Ks + nb + 4096 + w * 1024);
            vvn0 = *(const v8s*)(vc0 + koff);
            vvn1 = *(const v8s*)(vc1 + koff);
        }
        const u16* Kb = Ks + cur * 4096;

        v4f s[4];
#pragma unroll
        for (int nt = 0; nt < 4; nt++) {
            const u16* Kr = Kb + ((nt * 16 + lr) << 6);
            v8s b0 = *(const v8s*)(Kr + colk);
            v8s b1 = *(const v8s*)(Kr + (colk ^ 32));
            v4f t = zero4;
            t = __builtin_amdgcn_mfma_f32_16x16x32_bf16(aq0, b0, t, 0, 0, 0);
            t = __builtin_amdgcn_mfma_f32_16x16x32_bf16(aq1, b1, t, 0, 0, 0);
            s[nt] = t;
        }
#pragma unroll
        for (int r = 0; r < 4; r++) {
            float mx = fmaxf(fmaxf(s[0][r], s[1][r]), fmaxf(s[2][r], s[3][r]));
#pragma unroll
            for (int off = 1; off < 16; off <<= 1) mx = fmaxf(mx, __shfl_xor(mx, off));
            float mn = fmaxf(m_r[r], mx);
            float al = __expf(m_r[r] - mn);
            float rs = 0.f;
            int qrow = lq * 4 + r;
            int pbase = qrow << 6;
            int pswz = (qrow & 7) << 3;
#pragma unroll
            for (int nt = 0; nt < 4; nt++) {
                float pv = __expf(s[nt][r] - mn);
                rs += pv;
                Pp[pbase + ((nt * 16 + lr) ^ pswz)] = f2b(pv);
            }
#pragma unroll
            for (int off = 1; off < 16; off <<= 1) rs += __shfl_xor(rs, off);
            l_r[r] = l_r[r] * al + rs;
            m_r[r] = mn;
#pragma unroll
            for (int nt = 0; nt < 4; nt++) oacc[nt][r] *= al;
        }
        // V transpose stores (indices precomputed; data prefetched last iter).
#pragma unroll
        for (int j = 0; j < 8; j++) {
            Vt[vt0[j]] = (u16)vv0[j];
            Vt[vt1[j]] = (u16)vv1[j];
        }
        __syncthreads();   // Vt visible (also drains kt+1 prefetches)
        // Pw is wave-private; same-wave DS ops are in-order.
        const u16* Pr = Pp + (lr << 6);
        v8s pa0 = *(const v8s*)(Pr + colk);
        v8s pa1 = *(const v8s*)(Pr + (colk ^ 32));
#pragma unroll
        for (int nt = 0; nt < 4; nt++) {
            const u16* Vr = Vt + ((nt * 16 + lr) << 6);
            int gv = (ss ^ (2 * nt + (lr >> 3))) << 3;
            int colv = (lq << 3) ^ gv;
            v8s vb0 = *(const v8s*)(Vr + colv);
            v8s vb1 = *(const v8s*)(Vr + (colv ^ 32));
            oacc[nt] = __builtin_amdgcn_mfma_f32_16x16x32_bf16(pa0, vb0, oacc[nt], 0, 0, 0);
            oacc[nt] = __builtin_amdgcn_mfma_f32_16x16x32_bf16(pa1, vb1, oacc[nt], 0, 0, 0);
        }
        vv0 = vvn0; vv1 = vvn1;
        cur ^= 1;
    }
    bool bad = false;
#pragma unroll
    for (int r = 0; r < 4; r++) {
        float inv = 1.f / l_r[r];
#pragma unroll
        for (int nt = 0; nt < 4; nt++) {
            float val = oacc[nt][r] * inv;
            bad |= badf(val);
            ao[(rowbase + q0 + w * 16 + lq * 4 + r) * 1024 + h64 + nt * 16 + lr] = f2b(val);
        }
    }
    if (__ballot(bad) && l == 0) atomicMin(diag, stage);
}

// ---------------------------------------------------------------------------
// LayerNorm over E=1024 (fp32 out, final).
// ---------------------------------------------------------------------------
template <int F32OUT>
__global__ __launch_bounds__(256) void ln_k(const float* __restrict__ x,
                                            const u16* __restrict__ g, const u16* __restrict__ bt,
                                            u16* __restrict__ outb, float* __restrict__ outf,
                                            int stage, int* __restrict__ diag)
{
    __shared__ float red[8];
    int row = blockIdx.x, t = threadIdx.x, w = t >> 6;
    const float* xr = x + (long)row * 1024;
    float v[4], s = 0.f, sq = 0.f;
#pragma unroll
    for (int i = 0; i < 4; i++) { v[i] = xr[i * 256 + t]; s += v[i]; sq += v[i] * v[i]; }
#pragma unroll
    for (int off = 1; off < 64; off <<= 1) { s += __shfl_xor(s, off); sq += __shfl_xor(sq, off); }
    if ((t & 63) == 0) { red[w] = s; red[4 + w] = sq; }
    __syncthreads();
    float S = red[0] + red[1] + red[2] + red[3];
    float SQ = red[4] + red[5] + red[6] + red[7];
    float mean = S * (1.f / 1024.f);
    float var = fmaxf(SQ * (1.f / 1024.f) - mean * mean, 0.f);
    float rs = rsqrtf(var + 1e-5f);
    bool bad = false;
#pragma unroll
    for (int i = 0; i < 4; i++) {
        int e = i * 256 + t;
        float r = (v[i] - mean) * rs * b2f(g[e]) + b2f(bt[e]);
        bad |= badf(r);
        if (F32OUT) outf[(long)row * 1024 + e] = r;
        else outb[(long)row * 1024 + e] = f2b(r);
    }
    if (__ballot(bad) && (t & 63) == 0) atomicMin(diag, stage);
}

// Fused LN1+LN2: same row stats (same x), two affines, one pass.
__global__ __launch_bounds__(256) void ln12_k(const float* __restrict__ x,
                                              const u16* __restrict__ g1, const u16* __restrict__ b1,
                                              const u16* __restrict__ g2, const u16* __restrict__ b2,
                                              u16* __restrict__ out1, u16* __restrict__ out2,
                                              int stage, int* __restrict__ diag)
{
    __shared__ float red[8];
    int row = blockIdx.x, t = threadIdx.x, w = t >> 6;
    const float* xr = x + (long)row * 1024;
    float v[4], s = 0.f, sq = 0.f;
#pragma unroll
    for (int i = 0; i < 4; i++) { v[i] = xr[i * 256 + t]; s += v[i]; sq += v[i] * v[i]; }
#pragma unroll
    for (int off = 1; off < 64; off <<= 1) { s += __shfl_xor(s, off); sq += __shfl_xor(sq, off); }
    if ((t & 63) == 0) { red[w] = s; red[4 + w] = sq; }
    __syncthreads();
    float S = red[0] + red[1] + red[2] + red[3];
    float SQ = red[4] + red[5] + red[6] + red[7];
    float mean = S * (1.f / 1024.f);
    float var = fmaxf(SQ * (1.f / 1024.f) - mean * mean, 0.f);
    float rs = rsqrtf(var + 1e-5f);
    bool bad = false;
#pragma unroll
    for (int i = 0; i < 4; i++) {
        int e = i * 256 + t;
        float nv = (v[i] - mean) * rs;
        float r1 = nv * b2f(g1[e]) + b2f(b1[e]);
        float r2 = nv * b2f(g2[e]) + b2f(b2[e]);
        bad |= badf(r1) | badf(r2);
        out1[(long)row * 1024 + e] = f2b(r1);
        out2[(long)row * 1024 + e] = f2b(r2);
    }
    if (__ballot(bad) && (t & 63) == 0) atomicMin(diag, stage);
}

// ---------------------------------------------------------------------------
// rowfuse: tr = tra + trb (split-K partials).
__global__ __launch_bounds__(256) void rowfuse_k(
    const u16* __restrict__ cls, const u16* __restrict__ gate,
    const float* __restrict__ tra, const float* __restrict__ trb,
    const u16* __restrict__ ne, const u16* __restrict__ eew, const u16* __restrict__ eeb,
    const float* __restrict__ eta_p, float* __restrict__ xbuf, u16* __restrict__ x1b,
    int stage, int* __restrict__ diag)
{
    __shared__ float red[16];
    int row = blockIdx.x, t = threadIdx.x, w = t >> 6;
    long base = (long)row * 1024;
    float ifc[4];
#pragma unroll
    for (int i = 0; i < 4; i++) {
        int e = i * 256 + t;
        ifc[i] = b2f(cls[base + e]) + b2f(gate[base + e]) * (tra[base + e] + trb[base + e]);
    }
    float mx = fmaxf(fmaxf(ifc[0], ifc[1]), fmaxf(ifc[2], ifc[3]));
#pragma unroll
    for (int off = 1; off < 64; off <<= 1) mx = fmaxf(mx, __shfl_xor(mx, off));
    if ((t & 63) == 0) red[w] = mx;
    __syncthreads();
    float MX = fmaxf(fmaxf(red[0], red[1]), fmaxf(red[2], red[3]));
    float s1 = 0.f, s2 = 0.f, dot = 0.f;
#pragma unroll
    for (int i = 0; i < 4; i++) {
        int e = i * 256 + t;
        float ex = expf(ifc[i] - MX);
        s1 += ex; s2 += ex * ifc[i]; dot += ifc[i] * b2f(eew[e]);
    }
#pragma unroll
    for (int off = 1; off < 64; off <<= 1) {
        s1 += __shfl_xor(s1, off); s2 += __shfl_xor(s2, off); dot += __shfl_xor(dot, off);
    }
    if ((t & 63) == 0) { red[4 + w] = s1; red[8 + w] = s2; red[12 + w] = dot; }
    __syncthreads();
    float S1 = red[4] + red[5] + red[6] + red[7];
    float S2 = red[8] + red[9] + red[10] + red[11];
    float DT = red[12] + red[13] + red[14] + red[15];
    float logZ = MX + logf(S1);
    float ent = logZ - S2 / S1;
    float bal = 1.f / (1.f + expf(-(DT + b2f(eeb[0]))));
    float fac = eta_p[0] * bal / (ent + 1e-6f);
    bool bad = false;
#pragma unroll
    for (int i = 0; i < 4; i++) {
        int e = i * 256 + t;
        float rg = ifc[i] + fac * b2f(ne[base + e]);
        float x1 = xbuf[base + e] + rg;
        bad |= badf(x1);
        xbuf[base + e] = x1;
        x1b[base + e] = f2b(x1);
    }
    if (__ballot(bad) && (t & 63) == 0) atomicMin(diag, stage);
}

// softmax over sim partials: v = (pa + pb) * 0.03125/max(T,1e-8).
__global__ __launch_bounds__(256) void softmax_k(const float* __restrict__ pa, const float* __restrict__ pb,
                                                 const float* __restrict__ tp, u16* __restrict__ out,
                                                 int stage, int* __restrict__ diag)
{
    __shared__ float red[8];
    int row = blockIdx.x, t = threadIdx.x, w = t >> 6;
    long base = (long)row * 1024;
    float sc = 0.03125f / fmaxf(tp[0], 1e-8f);
    float v[4];
#pragma unroll
    for (int i = 0; i < 4; i++) v[i] = (pa[base + i * 256 + t] + pb[base + i * 256 + t]) * sc;
    float mx = fmaxf(fmaxf(v[0], v[1]), fmaxf(v[2], v[3]));
#pragma unroll
    for (int off = 1; off < 64; off <<= 1) mx = fmaxf(mx, __shfl_xor(mx, off));
    if ((t & 63) == 0) red[w] = mx;
    __syncthreads();
    float MX = fmaxf(fmaxf(red[0], red[1]), fmaxf(red[2], red[3]));
    float s = 0.f;
#pragma unroll
    for (int i = 0; i < 4; i++) { v[i] = expf(v[i] - MX); s += v[i]; }
#pragma unroll
    for (int off = 1; off < 64; off <<= 1) s += __shfl_xor(s, off);
    if ((t & 63) == 0) red[4 + w] = s;
    __syncthreads();
    float inv = 1.f / (red[4] + red[5] + red[6] + red[7]);
    bool bad = false;
#pragma unroll
    for (int i = 0; i < 4; i++) {
        float o = v[i] * inv;
        bad |= badf(o);
        out[base + i * 256 + t] = f2b(o);
    }
    if (__ballot(bad) && (t & 63) == 0) atomicMin(diag, stage);
}

// Fused dtype-convert + transpose: src [R,C] -> dst bf16 [C,R]. Check fused (stage 2).
__global__ void transpose_ft_k(const void* __restrict__ in, u16* __restrict__ out,
                               int R, int C, const int* __restrict__ flags, int idx,
                               int* __restrict__ diag)
{
    __shared__ u16 tile[32][33];
    int f = flags[idx];
    int x = blockIdx.x * 32 + threadIdx.x;
    int y0 = blockIdx.y * 32;
#pragma unroll
    for (int j = 0; j < 4; j++) {
        long src = (long)(y0 + threadIdx.y + j * 8) * C + x;
        tile[threadIdx.y + j * 8][threadIdx.x] =
            f ? f2b(((const float*)in)[src]) : ((const u16*)in)[src];
    }
    __syncthreads();
    int ox = y0 + threadIdx.x;
    int oy0 = blockIdx.x * 32;
    bool bad = false;
#pragma unroll
    for (int j = 0; j < 4; j++) {
        u16 u = tile[threadIdx.x][threadIdx.y + j * 8];
        bad |= ((u & 0x7FFF) >= 0x7F80);
        out[(long)(oy0 + threadIdx.y + j * 8) * R + ox] = u;
    }
    if (__ballot(bad) && ((threadIdx.y * 32 + threadIdx.x) & 63) == 0) atomicMin(diag, 2);
}

// Plain bf16 transpose (for quantum^T), batched via z.
__global__ void transpose_k(const u16* __restrict__ in, u16* __restrict__ out,
                            int R, int C, long sIn, long sOut)
{
    __shared__ u16 tile[32][33];
    int z = blockIdx.z;
    in += (long)z * sIn; out += (long)z * sOut;
    int x = blockIdx.x * 32 + threadIdx.x;
    int y0 = blockIdx.y * 32;
#pragma unroll
    for (int j = 0; j < 4; j++)
        tile[threadIdx.y + j * 8][threadIdx.x] = in[(long)(y0 + threadIdx.y + j * 8) * C + x];
    __syncthreads();
    int ox = y0 + threadIdx.x;
    int oy0 = blockIdx.x * 32;
#pragma unroll
    for (int j = 0; j < 4; j++)
        out[(long)(oy0 + threadIdx.y + j * 8) * R + ox] = tile[threadIdx.x][threadIdx.y + j * 8];
}

__global__ __launch_bounds__(256) void init_k(const void* __restrict__ xin, const int* __restrict__ flags,
                                              float* __restrict__ xbuf,
                                              float* __restrict__ ksf, u16* __restrict__ ksb,
                                              int* __restrict__ diag)
{
    int t = threadIdx.x;
    int f = flags[0];
    long base = (long)blockIdx.x * 1024;
    bool bad = false;
#pragma unroll
    for (int i = 0; i < 4; i++) {
        long idx = base + i * 256 + t;
        float xv = f ? ((const float*)xin)[idx] : b2f(((const u16*)xin)[idx]);
        bad |= badf(xv);
        xbuf[idx] = xv; ksf[idx] = xv; ksb[idx] = f2b(xv);
    }
    if (__ballot(bad) && (t & 63) == 0) atomicMin(diag, 1);
}

// ---------------------------------------------------------------------------
extern "C" void kernel_launch(void* const* d_in, const int* in_sizes, int n_in,
                              void* d_out, int out_size, void* d_ws, size_t ws_size,
                              hipStream_t stream)
{
    const size_t MB = 1u << 20;
    float* outf = (float*)d_out;
    if (ws_size < 192 * MB) {
        int code = (int)(ws_size >> 25); if (code > 9) code = 9;
        small_k<<<1, 64, 0, stream>>>(outf, code);
        return;
    }
    const u16* s_refg = (const u16*)d_in[11];
    const u16* s_temp = (const u16*)d_in[18];
    const u16* s_eta  = (const u16*)d_in[23];
    const u16* s_obsg = (const u16*)d_in[36];

    InArr IA;
    for (int i = 0; i < 37; i++) { IA.p[i] = d_in[i]; IA.n[i] = (i < n_in) ? in_sizes[i] : 0; }

    char* ws = (char*)d_ws;
    // Weight slots: srv merged [2048,1024] at 0MB, qk merged [2048,1024] at 4MB.
    u16* srT  = (u16*)(ws + 0 * MB);    // sr rows 0-1023
    u16* vT   = (u16*)(ws + 2 * MB);    // v rows 1024-2047 (contiguous with srT)
    u16* qT   = (u16*)(ws + 4 * MB);    // q rows 0-1023
    u16* kT   = (u16*)(ws + 6 * MB);    // k rows 1024-2047 (contiguous with qT)
    u16* oT   = (u16*)(ws + 8 * MB);
    u16* cT   = (u16*)(ws + 10 * MB);
    u16* qpT  = (u16*)(ws + 12 * MB);
    u16* kpT  = (u16*)(ws + 14 * MB);
    u16* obsT = (u16*)(ws + 16 * MB);
    u16* igT  = (u16*)(ws + 18 * MB);   // [1024,2048]
    u16* f1T  = (u16*)(ws + 22 * MB);   // [4096,1024]
    u16* f2T  = (u16*)(ws + 30 * MB);   // [1024,4096]
    float* scal = (float*)(ws + 38 * MB);
    int* diag  = (int*)(ws + 38 * MB + 64);
    int* flags = (int*)(ws + 38 * MB + 128);
    int* cnt   = (int*)(ws + 38 * MB + 512);
    u16* BIA   = (u16*)(ws + 38 * MB + 8192);
    // Bias layout: sr|v contiguous (merged srv), q|k contiguous (merged qk).
    u16* c_bsr = BIA + 0*1024,  *c_bv = BIA + 1*1024;
    u16* c_bq  = BIA + 2*1024,  *c_bk = BIA + 3*1024;
    u16* c_bo  = BIA + 4*1024,  *c_bc = BIA + 5*1024;
    u16* c_bqp = BIA + 6*1024,  *c_big = BIA + 7*1024, *c_bkp = BIA + 8*1024;
    u16* c_bobs= BIA + 9*1024,  *c_bf2 = BIA + 10*1024;
    u16* c_g1  = BIA + 11*1024, *c_be1 = BIA + 12*1024;
    u16* c_g2  = BIA + 13*1024, *c_be2 = BIA + 14*1024;
    u16* c_g3  = BIA + 15*1024, *c_be3 = BIA + 16*1024;
    u16* c_eew = BIA + 17*1024, *c_eeb = BIA + 18*1024;
    u16* c_bf1 = BIA + 19*1024;
    float* xbuf = (float*)(ws + 40 * MB);
    float* ksf  = (float*)(ws + 56 * MB);
    u16* ksb    = (u16*)(ws + 72 * MB);
    u16* xn     = (u16*)(ws + 80 * MB);
    u16* xn2    = (u16*)(ws + 88 * MB);
    u16* xr     = (u16*)(ws + 96 * MB);
    u16* qb     = (u16*)(ws + 104 * MB);
    u16* kb     = (u16*)(ws + 112 * MB);
    u16* vb     = (u16*)(ws + 120 * MB);
    u16* aob    = (u16*)(ws + 128 * MB);
    u16* quant  = (u16*)(ws + 136 * MB);
    u16* hb     = (u16*)(ws + 144 * MB);  // 32 MB (144-176); dead after f2c
    u16* clsb   = (u16*)(ws + 176 * MB);
    u16* neb    = (u16*)(ws + 184 * MB);
    // Serially reused fp32 partial slots (16MB each at 144/160MB):
    //  ig -> igc; sim -> softmax; trf -> rowfuse.
    // f2 partials at 104/120MB (qb..aob dead at f2 time).
    float* f2pa = (float*)(ws + 104 * MB);
    float* f2pb = (float*)(ws + 120 * MB);
    float* ppa  = (float*)(ws + 144 * MB);
    float* ppb  = (float*)(ws + 160 * MB);
    u16* quantT = xn;
    u16* cpb = qb;  u16* qpb = kb;  u16* gateb = vb;  u16* attw = aob;  u16* x1b = xr;

    const long BS1 = 1024L * 1024L;
    const int KBIG = 1 << 30;
    dim3 tb(32, 8), blk(256), gblk(512);
    GJ2 J0 = {nullptr, nullptr, nullptr, nullptr};

    auto G = [&](int epi, int gx, int gy, int gz,
                 const u16* A, int lda, long sA, const u16* A2, int ksp,
                 const u16* Bt, int ldb, long sB, const u16* bias,
                 u16* obf, float* of32, int ldc, long sC, int K,
                 const float* scp, const u16* aux, float* xa, float* kf, u16* kb2, float* kso,
                 GJ2 J2, int stg) {
        dim3 grid(gx, gy, gz);
        switch (epi) {
            case 0: gemm_bt<0><<<grid, gblk, 0, stream>>>(A, lda, sA, A2, ksp, Bt, ldb, sB, bias, obf, of32, ldc, sC, K, scp, aux, xa, kf, kb2, kso, J2, stg, diag); break;
            case 2: gemm_bt<2><<<grid, gblk, 0, stream>>>(A, lda, sA, A2, ksp, Bt, ldb, sB, bias, obf, of32, ldc, sC, K, scp, aux, xa, kf, kb2, kso, J2, stg, diag); break;
            case 5: gemm_bt<5><<<grid, gblk, 0, stream>>>(A, lda, sA, A2, ksp, Bt, ldb, sB, bias, obf, of32, ldc, sC, K, scp, aux, xa, kf, kb2, kso, J2, stg, diag); break;
            case 6: gemm_bt<6><<<grid, gblk, 0, stream>>>(A, lda, sA, A2, ksp, Bt, ldb, sB, bias, obf, of32, ldc, sC, K, scp, aux, xa, kf, kb2, kso, J2, stg, diag); break;
            case 7: gemm_bt<7><<<grid, gblk, 0, stream>>>(A, lda, sA, A2, ksp, Bt, ldb, sB, bias, obf, of32, ldc, sC, K, scp, aux, xa, kf, kb2, kso, J2, stg, diag); break;
            case 8: gemm_bt<8><<<grid, gblk, 0, stream>>>(A, lda, sA, A2, ksp, Bt, ldb, sB, bias, obf, of32, ldc, sC, K, scp, aux, xa, kf, kb2, kso, J2, stg, diag); break;
        }
    };

    // ---- setup ----
    reset_k<<<1, 256, 0, stream>>>(diag, cnt);
    classify_k<<<dim3(8, 37), blk, 0, stream>>>(IA, cnt);
    finalize_k<<<1, 64, 0, stream>>>(IA, cnt, flags);
    decode_scalars_k<<<1, 64, 0, stream>>>(s_refg, s_temp, s_eta, s_obsg, scal);
    // Bias/1D jobs. Order: sr,v | q,k contiguous for the merged GEMMs.
    BJobs BJ = {
        {2, 8, 4, 6, 10, 13, 15, 17, 20, 35, 27, 28, 29, 30, 31, 32, 33, 21, 22, 25},
        {0, 1, 2, 3, 4, 5, 6, 7, 8, 9, 10, 11, 12, 13, 14, 15, 16, 17, 18, 19},
        {1024,1024,1024,1024,1024,1024,1024,1024,1024,1024,1024,1024,1024,1024,1024,1024,1024,1024,1,4096}
    };
    cvt1d_k<<<dim3(4, 20), blk, 0, stream>>>(IA, BJ, flags, BIA);
    struct WT { int idx; u16* dst; long n; int R, C, gx, gy; };
    WT wts[12] = {
        {1, srT, 1048576, 1024, 1024, 32, 32},  {7, vT, 1048576, 1024, 1024, 32, 32},
        {3, qT, 1048576, 1024, 1024, 32, 32},   {5, kT, 1048576, 1024, 1024, 32, 32},
        {9, oT, 1048576, 1024, 1024, 32, 32},   {12, cT, 1048576, 1024, 1024, 32, 32},
        {14, qpT, 1048576, 1024, 1024, 32, 32}, {19, kpT, 1048576, 1024, 1024, 32, 32},
        {34, obsT, 1048576, 1024, 1024, 32, 32},
        {16, igT, 2097152, 2048, 1024, 32, 64},
        {24, f1T, 4194304, 1024, 4096, 128, 32},
        {26, f2T, 4194304, 4096, 1024, 32, 128},
    };
    for (int i = 0; i < 12; i++) {
        transpose_ft_k<<<dim3(wts[i].gx, wts[i].gy, 1), tb, 0, stream>>>(
            d_in[wts[i].idx], wts[i].dst, wts[i].R, wts[i].C, flags, wts[i].idx, diag);
    }
    init_k<<<4096, blk, 0, stream>>>(d_in[0], flags, xbuf, ksf, ksb, diag);
    chk_scal_k<<<1, 64, 0, stream>>>(scal, diag);

    for (int it = 0; it < 3; it++) {
        int sb = 4 + it * 20;
        // fused ln1+ln2 (same stats): xn + xn2 in one xbuf pass.
        ln12_k<<<4096, blk, 0, stream>>>(xbuf, c_g1, c_be1, c_g2, c_be2, xn, xn2, sb + 0, diag);
        // merged sr|v: N=2048, A=xn. col<1024 -> xr (SR residual), else -> vb.
        GJ2 Jsrv = {nullptr, nullptr, nullptr, vb};
        G(6, 16, 32, 1, xn, 1024, 0, nullptr, KBIG, srT, 1024, 0, c_bsr, xr, nullptr, 1024, 0, 1024, scal + 0, xn, nullptr, nullptr, nullptr, nullptr, Jsrv, sb + 1);
        // merged q|k: N=2048, A=xr. col<1024 -> qb (pre-scaled 0.125), else -> kb.
        GJ2 Jqk = {nullptr, nullptr, nullptr, kb};
        G(7, 16, 32, 1, xr, 1024, 0, nullptr, KBIG, qT, 1024, 0, c_bq, qb, nullptr, 1024, 0, 1024, nullptr, nullptr, nullptr, nullptr, nullptr, nullptr, Jqk, sb + 2);
        // flash (non-split, direct bf16 out).
        flash_k<<<dim3(16, 64), blk, 0, stream>>>(qb, kb, vb, aob, sb + 5, diag);
        // dual (o, kp): z0 A=aob->quant, z1 A=ksb->neb.
        GJ2 Jokp = {ksb, kpT, c_bkp, neb};
        G(0, 8, 32, 2, aob, 1024, 0, nullptr, KBIG, oT, 1024, 0, c_bo, quant, nullptr, 1024, 0, 1024, nullptr, nullptr, nullptr, nullptr, nullptr, nullptr, Jokp, sb + 6);
        transpose_k<<<dim3(32, 32, 4), tb, 0, stream>>>(quant, quantT, 1024, 1024, BS1, BS1);
        G(2, 32, 32, 1, xn2, 1024, 0, nullptr, KBIG, f1T, 1024, 0, c_bf1, hb, nullptr, 4096, 0, 1024, nullptr, nullptr, nullptr, nullptr, nullptr, nullptr, J0, sb + 8);
        // f2 split-K=2: fp32 partials into f2pa/f2pb (dead qb..aob region).
        G(8, 8, 32, 2, hb, 4096, 2048, nullptr, KBIG, f2T, 4096, 2048, nullptr, nullptr, f2pa, 1024, 4194304, 2048, nullptr, nullptr, nullptr, nullptr, nullptr, nullptr, J0, sb + 9);
        f2c_k<<<4096, blk, 0, stream>>>(f2pa, f2pb, c_bf2, clsb, sb + 9, diag);
        // dual (c, qp): z0 A=clsb->cpb, z1 A=quant->qpb.
        GJ2 Jcqp = {quant, qpT, c_bqp, qpb};
        G(0, 8, 32, 2, clsb, 1024, 0, nullptr, KBIG, cT, 1024, 0, c_bc, cpb, nullptr, 1024, 0, 1024, nullptr, nullptr, nullptr, nullptr, nullptr, nullptr, Jcqp, sb + 10);
        // ig split-K=2 via dual-job: z0 = cpb x igT[:, :1024] -> ppa,
        // z1 = qpb x igT[:, 1024:] -> ppb. Combine adds bias + sigmoid.
        GJ2 Jig = {qpb, igT + 1024, nullptr, (u16*)ppb};
        G(8, 8, 32, 2, cpb, 1024, 0, nullptr, KBIG, igT, 2048, 0, nullptr, nullptr, ppa, 1024, 0, 1024, nullptr, nullptr, nullptr, nullptr, nullptr, nullptr, Jig, sb + 12);
        igc_k<<<4096, blk, 0, stream>>>(ppa, ppb, c_big, gateb, sb + 12, diag);
        // sim split-K=2, batched z=4: grid (8,8,8). Halves of K=1024 at +512.
        GJ2 Jsim = {cpb + 512, qpb + 512, nullptr, (u16*)ppb};
        G(8, 8, 8, 8, cpb, 1024, BS1, nullptr, KBIG, qpb, 1024, BS1, nullptr, nullptr, ppa, 1024, BS1, 512, nullptr, nullptr, nullptr, nullptr, nullptr, nullptr, Jsim, sb + 14);
        softmax_k<<<4096, blk, 0, stream>>>(ppa, ppb, scal + 1, attw, sb + 15, diag);
        // trf split-K=2, batched z=4 (sim partials consumed by softmax above).
        GJ2 Jtrf = {attw + 512, quantT + 512, nullptr, (u16*)ppb};
        G(8, 8, 8, 8, attw, 1024, BS1, nullptr, KBIG, quantT, 1024, BS1, nullptr, nullptr, ppa, 1024, BS1, 512, nullptr, nullptr, nullptr, nullptr, nullptr, nullptr, Jtrf, sb + 16);
        rowfuse_k<<<4096, blk, 0, stream>>>(clsb, gateb, ppa, ppb, neb, c_eew, c_eeb, scal + 2, xbuf, x1b, sb + 17, diag);
        float* kso = (it == 2) ? (outf + 4194304) : nullptr;
        G(5, 8, 32, 1, x1b, 1024, 0, nullptr, KBIG, obsT, 1024, 0, c_bobs, nullptr, nullptr, 1024, 0, 1024, scal + 3, nullptr, xbuf, ksf, ksb, kso, J0, sb + 18);
    }
    ln_k<1><<<4096, blk, 0, stream>>>(xbuf, c_g3, c_be3, nullptr, outf, 70, diag);
    fin32_k<<<1024, blk, 0, stream>>>(outf, 2097152, diag);
}

// Round 13
// 1515.906 us; speedup vs baseline: 1.0855x; 1.0855x over previous
//
#include <hip/hip_runtime.h>
#include <hip/hip_bf16.h>
#include <cmath>

// RecursiveQuantumTransformerLayer on MI355X (gfx950).
// B=4, S=1024, E=1024, H=16, D=64, F=4096, DEPTH=3.
// [Round 20: consolidation. R19's BK=32 dbuf gemm REGRESSED (1520->1645):
//  doubling barrier count halved per-barrier MFMA cover (8 mfma ~64cy vs
//  ~500cy load latency) -- occupancy can't fix an exposed-latency schedule.
//  Reverted gemm_bt to R18's BK=64 double-buffer (measured best: 1520).
//  Kept R19's non-split direct flash (correct half of R19: 81.7us, no
//  flashc, no 48MB partial traffic). No new mechanisms.]

typedef unsigned short u16;
typedef short v8s __attribute__((ext_vector_type(8)));
typedef float v4f __attribute__((ext_vector_type(4)));
typedef unsigned short u16x4 __attribute__((ext_vector_type(4)));
typedef unsigned int u32x4 __attribute__((ext_vector_type(4)));

#define DEV __device__ __forceinline__

DEV float b2f(u16 u) { return __uint_as_float(((unsigned int)u) << 16); }
DEV u16 f2b(float f) {
    unsigned int x = __float_as_uint(f);
    return (u16)((x + 0x7fffu + ((x >> 16) & 1u)) >> 16);  // RNE
}
DEV bool badf(float f) { return ((__float_as_uint(f) >> 23) & 0xFF) == 0xFF; }

DEV void async16(const void* g, void* l) {
    __builtin_amdgcn_global_load_lds((const __attribute__((address_space(1))) void*)g,
                                     (__attribute__((address_space(3))) void*)l, 16, 0, 0);
}

struct InArr { const void* p[37]; int n[37]; };
struct BJobs { int si[20]; int off[20]; int n[20]; };
struct GJ2 { const u16* jA; const u16* jB; const u16* jbias; u16* jout; };

#define CLS_CAP 16384  // pairs sampled per input (64 KB), 8 chunks x 2048

// ---------------- setup / diagnostics ----------------
__global__ void reset_k(int* diag, int* cnt) {
    if (threadIdx.x == 0) *diag = 0x7FFFFFFF;
    if (threadIdx.x < 80) cnt[threadIdx.x] = 0;
}

__global__ void classify_k(InArr A, int* cnt) {
    int i = blockIdx.y;
    int n = A.n[i];
    if (n <= 1) return;
    long pairs = (long)n >> 1;
    int wild = 0, pz = 0;
    if (pairs > (long)(2 * CLS_CAP)) {
        // Sampled: 8 evenly spaced chunks of 2048 pairs, u32x4 vector loads.
        const unsigned int* q32 = (const unsigned int*)A.p[i];
        long p0 = ((long)blockIdx.x * (pairs >> 3)) & ~3L;
        long tbase = p0 + (long)threadIdx.x * 8;
#pragma unroll
        for (int c = 0; c < 2; c++) {
            u32x4 v = *(const u32x4*)(q32 + tbase + c * 4);
#pragma unroll
            for (int j = 0; j < 4; j++) {
                unsigned int p = v[j];
                u16 w0 = (u16)(p & 0xFFFFu), w1 = (u16)(p >> 16);
                wild += ((w0 & 0x7FFF) >= 0x5000) + ((w1 & 0x7FFF) >= 0x5000);
                pz += (w0 == 0 && w1 >= 0x3000 && w1 <= 0x4100) ? 1 : 0;
            }
        }
    } else {
        const u16* q = (const u16*)A.p[i];
        long stride = (long)gridDim.x * blockDim.x;
        for (long j = (long)blockIdx.x * blockDim.x + threadIdx.x; j < pairs; j += stride) {
            u16 w0 = q[2 * j], w1 = q[2 * j + 1];
            wild += ((w0 & 0x7FFF) >= 0x5000) + ((w1 & 0x7FFF) >= 0x5000);
            pz += (w0 == 0 && w1 >= 0x3000 && w1 <= 0x4100) ? 1 : 0;
        }
    }
#pragma unroll
    for (int off = 1; off < 64; off <<= 1) {
        wild += __shfl_xor(wild, off);
        pz += __shfl_xor(pz, off);
    }
    if ((threadIdx.x & 63) == 0) {
        atomicAdd(&cnt[2 * i], wild);
        atomicAdd(&cnt[2 * i + 1], pz);
    }
}

__global__ void finalize_k(InArr A, const int* cnt, int* flags) {
    int i = threadIdx.x;
    if (i < 37) {
        int n = A.n[i];
        int f = 0;
        if (n > 1) {
            long pairs = (long)n >> 1;
            long wthr, pthr;
            if (pairs > (long)(2 * CLS_CAP)) { wthr = (2L * CLS_CAP) >> 6; pthr = (long)CLS_CAP >> 2; }
            else { wthr = (long)n >> 6; pthr = (long)n >> 3; }
            f = (cnt[2 * i] > wthr) || (cnt[2 * i + 1] > pthr);
        }
        flags[i] = f;
    }
}

DEV float dec_scalar(const u16* p) {
    float bf = b2f(p[0]);
    if (bf > 0.0009765625f && bf < 8.0f) return bf;
    unsigned int w = (((unsigned int)p[1]) << 16) | (unsigned int)p[0];
    return __uint_as_float(w);
}

__global__ void decode_scalars_k(const u16* rg, const u16* tp, const u16* et,
                                 const u16* og, float* out)
{
    if (threadIdx.x == 0 && blockIdx.x == 0) {
        out[0] = dec_scalar(rg);
        out[1] = dec_scalar(tp);
        out[2] = dec_scalar(et);
        out[3] = dec_scalar(og);
    }
}

__global__ void cvt1d_k(InArr A, BJobs J, const int* flags, u16* BIA) {
    int j = blockIdx.y;
    int n = J.n[j];
    int si = J.si[j];
    const void* src = A.p[si];
    u16* dst = BIA + (long)J.off[j] * 1024;
    int f = flags[si];
    int stride = gridDim.x * blockDim.x;
    for (int i = blockIdx.x * blockDim.x + threadIdx.x; i < n; i += stride) {
        dst[i] = f ? f2b(((const float*)src)[i]) : ((const u16*)src)[i];
    }
}

__global__ void chk_scal_k(const float* scal, int* diag) {
    if (threadIdx.x == 0) {
        for (int i = 0; i < 4; i++) {
            float v = scal[i];
            if (!(v > 0.f && v < 8.f)) atomicMin(diag, 3);
        }
    }
}

// Sanitize fp32 outputs; if a stage fired, encode it at out[0] (fp32).
__global__ void fin32_k(float* out, long n4, const int* diag) {
    long stride = (long)gridDim.x * blockDim.x;
    long i0 = (long)blockIdx.x * blockDim.x + threadIdx.x;
    v4f* o4 = (v4f*)out;
    for (long i = i0; i < n4; i += stride) {
        v4f v = o4[i];
        bool b = false;
#pragma unroll
        for (int j = 0; j < 4; j++) b |= badf(v[j]);
        if (b) {
#pragma unroll
            for (int j = 0; j < 4; j++) if (badf(v[j])) v[j] = 0.f;
            o4[i] = v;
        }
    }
    if (i0 == 0) {
        int d = *diag;
        if (d != 0x7FFFFFFF) out[0] = 200.f + 4.f * (float)(d < 70 ? d : 70);
    }
}

__global__ void small_k(float* out, int code) {
    if (threadIdx.x == 0 && blockIdx.x == 0) out[0] = 900.f + 4.f * code;
}

// f2 split-K combine: out = bf16(a + b + bias), fused NaN check.
__global__ __launch_bounds__(256) void f2c_k(const float* __restrict__ a, const float* __restrict__ b,
                                             const u16* __restrict__ bias, u16* __restrict__ out,
                                             int stage, int* __restrict__ diag)
{
    long i0 = ((long)blockIdx.x * 256 + threadIdx.x) * 4;
    v4f va = *(const v4f*)(a + i0);
    v4f vb = *(const v4f*)(b + i0);
    int colb = (int)(i0 & 1023);
    bool bad = false;
    u16x4 o;
#pragma unroll
    for (int j = 0; j < 4; j++) {
        float r = va[j] + vb[j] + b2f(bias[colb + j]);
        bad |= badf(r);
        o[j] = f2b(r);
    }
    *(u16x4*)(out + i0) = o;
    if (__ballot(bad) && (threadIdx.x & 63) == 0) atomicMin(diag, stage);
}

// ig split-K combine: gate = sigmoid(a + b + bias), fused NaN check.
__global__ __launch_bounds__(256) void igc_k(const float* __restrict__ a, const float* __restrict__ b,
                                             const u16* __restrict__ bias, u16* __restrict__ out,
                                             int stage, int* __restrict__ diag)
{
    long i0 = ((long)blockIdx.x * 256 + threadIdx.x) * 4;
    v4f va = *(const v4f*)(a + i0);
    v4f vb = *(const v4f*)(b + i0);
    int colb = (int)(i0 & 1023);
    bool bad = false;
    u16x4 o;
#pragma unroll
    for (int j = 0; j < 4; j++) {
        float r = 1.f / (1.f + expf(-(va[j] + vb[j] + b2f(bias[colb + j]))));
        bad |= badf(r);
        o[j] = f2b(r);
    }
    *(u16x4*)(out + i0) = o;
    if (__ballot(bad) && (threadIdx.x & 63) == 0) atomicMin(diag, stage);
}

// ---------------------------------------------------------------------------
// GEMM: C[M,N] = A[M,K] * Bt[N,K]^T (+bias) with fused epilogues.
// 128x128 tile, BK=64, DOUBLE-BUFFERED LDS (64KB): next tile's async16
// issued before current tile's ds_read+MFMA; ONE barrier per K-step.
// XOR-swizzled stride-64 LDS rows (conflict-free). 512 threads (8 waves
// 2Mx4N, each 64x32 = 4x2 mfma 16x16x32). XCD-chunked block swizzle.
// EPI: 0=bias, 2=GELU, 5=OBS,
//      6=dual-out (col<1024: SR residual -> obf; col>=1024 -> J2.jout),
//      7=dual-out plain, col<1024 scaled by 0.125 (q for flash; exact 2^-3),
//      8=fp32 partial (no bias; split-K; dual-job -> (float*)J2.jout).
// J2.jA != null => dual-job: z >= gridDim.z/2 switches {A,Bt,bias,out}.
// Output NaN/Inf check fused (ballot+atomicMin(diag,stage)).
// ---------------------------------------------------------------------------
template <int EPI>
__global__ __launch_bounds__(512) void gemm_bt(
    const u16* __restrict__ A, int lda, long sA,
    const u16* __restrict__ A2, int ksplit,
    const u16* __restrict__ Bt, int ldb, long sB,
    const u16* __restrict__ bias,
    u16* __restrict__ obf, float* __restrict__ of32, int ldc, long sC,
    int K,
    const float* __restrict__ scp,
    const u16* __restrict__ aux,
    float* __restrict__ xaux, float* __restrict__ ksf, u16* __restrict__ ksb,
    float* __restrict__ kso,
    GJ2 J2,
    int stage, int* __restrict__ diag)
{
    __shared__ __align__(16) u16 As[2 * 128 * 64];
    __shared__ __align__(16) u16 Bs[2 * 128 * 64];
    const int tid = threadIdx.x;
    const int w = tid >> 6, l = tid & 63;
    const int lr = l & 15, lq = l >> 4;

    // Bijective XCD-chunked swizzle over the whole grid (x-major flat id).
    const int gx = gridDim.x, gy = gridDim.y;
    const int nwg = gx * gy * (int)gridDim.z;
    int flat = blockIdx.x + gx * (blockIdx.y + gy * blockIdx.z);
    int qq = nwg >> 3, rr = nwg & 7;
    int xcd = flat & 7, loc = flat >> 3;
    int nf = (xcd < rr ? xcd * (qq + 1) : rr * (qq + 1) + (xcd - rr) * qq) + loc;
    const int bx = nf % gx;
    int tmp = nf / gx;
    const int by = tmp % gy;
    int z = tmp / gy;

    // Dual-job pointer switch (upper half of z selects job B).
    const u16* Aj = A; const u16* Bj = Bt; const u16* biasj = bias; u16* obfj = obf;
    float* of32j = of32;
    if (J2.jA) {
        int jzs = (int)gridDim.z >> 1;
        if (z >= jzs) {
            Aj = J2.jA; Bj = J2.jB; biasj = J2.jbias;
            if (EPI == 8) of32j = (float*)J2.jout; else obfj = J2.jout;
            z -= jzs;
        }
    }

    const int m0 = by * 128, n0 = bx * 128;
    const u16* Az = Aj + (long)z * sA;
    const u16* Bz = Bj + (long)z * sB;
    const int wm = (w >> 2) * 64, wn = (w & 3) * 32;

    v4f zero4 = {0.f, 0.f, 0.f, 0.f};
    v4f acc[4][2];
#pragma unroll
    for (int i = 0; i < 4; i++)
#pragma unroll
        for (int j = 0; j < 2; j++) acc[i][j] = zero4;

    const int swz = lr & 7;
    const int c0s = (lq ^ swz) << 3;         // chunk slot for kk=0
    const int c1s = ((lq + 4) ^ swz) << 3;   // chunk slot for kk=32
    // Staging constants.
    const int srow = tid >> 3;               // 0..63 (pass adds 64)
    const int ssc = (((tid & 7) ^ (srow & 7)) * 8);

    // Prologue: stage k0=0 into buffer 0.
    {
        const u16* Ab = (0 < ksplit) ? Az : A2;
#pragma unroll
        for (int p = 0; p < 2; p++) {
            int row = p * 64 + srow;
            async16(Ab + (long)(m0 + row) * lda + ssc, (char*)As + p * 8192 + w * 1024);
            async16(Bz + (long)(n0 + row) * ldb + ssc, (char*)Bs + p * 8192 + w * 1024);
        }
    }
    __syncthreads();
    int cur = 0;
    for (int k0 = 0; k0 < K; k0 += 64) {
        int kn = k0 + 64;
        if (kn < K) {
            const u16* Ab = (kn < ksplit) ? (Az + kn) : (A2 + (kn - ksplit));
            int nb = (cur ^ 1) * 16384;
#pragma unroll
            for (int p = 0; p < 2; p++) {
                int row = p * 64 + srow;
                async16(Ab + (long)(m0 + row) * lda + ssc, (char*)As + nb + p * 8192 + w * 1024);
                async16(Bz + (long)(n0 + row) * ldb + kn + ssc, (char*)Bs + nb + p * 8192 + w * 1024);
            }
        }
        const u16* Asc = As + cur * 8192;
        const u16* Bsc = Bs + cur * 8192;
        v8s av0[4], av1[4], bv0[2], bv1[2];
#pragma unroll
        for (int mi = 0; mi < 4; mi++) {
            const u16* Ar = Asc + ((wm + mi * 16 + lr) << 6);
            av0[mi] = *(const v8s*)(Ar + c0s);
            av1[mi] = *(const v8s*)(Ar + c1s);
        }
#pragma unroll
        for (int ni = 0; ni < 2; ni++) {
            const u16* Br = Bsc + ((wn + ni * 16 + lr) << 6);
            bv0[ni] = *(const v8s*)(Br + c0s);
            bv1[ni] = *(const v8s*)(Br + c1s);
        }
#pragma unroll
        for (int mi = 0; mi < 4; mi++)
#pragma unroll
            for (int ni = 0; ni < 2; ni++)
                acc[mi][ni] = __builtin_amdgcn_mfma_f32_16x16x32_bf16(av0[mi], bv0[ni], acc[mi][ni], 0, 0, 0);
#pragma unroll
        for (int mi = 0; mi < 4; mi++)
#pragma unroll
            for (int ni = 0; ni < 2; ni++)
                acc[mi][ni] = __builtin_amdgcn_mfma_f32_16x16x32_bf16(av1[mi], bv1[ni], acc[mi][ni], 0, 0, 0);
        __syncthreads();   // drains next-tile prefetch; frees cur for overwrite
        cur ^= 1;
    }

    float gsv = 0.f;
    if (EPI == 5 || EPI == 6) gsv = scp[0];
    bool bad = false;
#pragma unroll
    for (int mi = 0; mi < 4; mi++) {
        int row = m0 + wm + mi * 16 + lq * 4;
#pragma unroll
        for (int ni = 0; ni < 2; ni++) {
            int col = n0 + wn + ni * 16 + lr;
            float bb = biasj ? b2f(biasj[col]) : 0.f;
#pragma unroll
            for (int r = 0; r < 4; r++) {
                float v = acc[mi][ni][r] + bb;
                if (EPI == 6 || EPI == 7) {
                    long rbase = (long)(row + r) * 1024;
                    float res;
                    if (col < 1024) {
                        if (EPI == 6) res = b2f(aux[rbase + col]) + gsv * v;
                        else res = v * 0.125f;   // q pre-scale (exact 2^-3)
                        bad |= badf(res);
                        obfj[rbase + col] = f2b(res);
                    } else {
                        res = v;
                        bad |= badf(res);
                        J2.jout[rbase + col - 1024] = f2b(res);
                    }
                } else {
                    long idx = (long)z * sC + (long)(row + r) * ldc + col;
                    float res = v;
                    if (EPI == 2) res = 0.5f * v * (1.f + erff(v * 0.70710678118654752f));
                    else if (EPI == 5) {
                        float xv = xaux[idx];
                        float nx = xv + gsv * v;
                        xaux[idx] = nx;
                        float kv = ksf[idx];
                        float kn = kv + 0.1f * (nx - kv);
                        ksf[idx] = kn;
                        ksb[idx] = f2b(kn);
                        if (kso) kso[idx] = kn;
                        bad |= badf(kn);
                        res = nx;
                    }
                    bad |= badf(res);
                    if (obfj) obfj[idx] = f2b(res);
                    if (of32j) of32j[idx] = res;
                }
            }
        }
    }
    if (__ballot(bad) && l == 0) atomicMin(diag, stage);
}

// ---------------------------------------------------------------------------
// Flash attention: grid (16 qtiles, 64 bh). 4 waves x 16 q-rows. D=64.
// Non-split direct bf16 output. XCD-locality remap: each XCD owns 8
// complete (b,h) groups. Ks double-buffered; K/V prefetch at loop top;
// Vt swizzle precomputed; q arrives pre-scaled by 0.125.
// ---------------------------------------------------------------------------
__global__ __launch_bounds__(256) void flash_k(
    const u16* __restrict__ q, const u16* __restrict__ k, const u16* __restrict__ v,
    u16* __restrict__ ao, int stage, int* __restrict__ diag)
{
    __shared__ __align__(16) u16 Ks[2 * 64 * 64];
    __shared__ __align__(16) u16 Vt[64 * 64];
    __shared__ __align__(16) u16 Pw[4 * 16 * 64];
    const int tid = threadIdx.x, w = tid >> 6, l = tid & 63;
    const int lr = l & 15, lq = l >> 4;
    // XCD-locality remap (grid is (16, 64), 1024 blocks, bijective).
    const int flat = blockIdx.x + (blockIdx.y << 4);
    const int xcd = flat & 7, loc = flat >> 3;      // loc 0..127
    const int bh = xcd * 8 + (loc >> 4);            // 8 bh per XCD
    const int q0 = (loc & 15) * 64;
    const int b = bh >> 4, h = bh & 15;
    const long rowbase = (long)b * 1024;
    const int h64 = h * 64;

    const u16* Qp = q + (rowbase + q0 + w * 16 + lr) * 1024 + h64;
    v8s aq0 = *(const v8s*)(Qp + lq * 8);
    v8s aq1 = *(const v8s*)(Qp + 32 + lq * 8);

    v4f zero4 = {0.f, 0.f, 0.f, 0.f};
    v4f oacc[4];
    float m_r[4], l_r[4];
#pragma unroll
    for (int i = 0; i < 4; i++) { oacc[i] = zero4; m_r[i] = -INFINITY; l_r[i] = 0.f; }

    const int ss = lr & 7;                 // row-swizzle bits for Ks/Pw reads
    const int colk = (lq ^ ss) << 3;       // swizzled column byte-slot (u16 units)
    u16* Pp = Pw + w * (16 * 64);

    // Staging constants (fixed per thread).
    const int c0 = tid, c1 = 256 + tid;
    const int row0 = c0 >> 3, cc0 = (c0 & 7) * 8;
    const int row1 = c1 >> 3, cc1 = (c1 & 7) * 8;
    const int sl0 = ((c0 & 7) ^ (row0 & 7)) * 8;
    const int sl1 = ((c1 & 7) ^ (row1 & 7)) * 8;
    int vt0[8], vt1[8];
#pragma unroll
    for (int j = 0; j < 8; j++) {
        int d0 = cc0 + j, g0 = (d0 & 7) ^ ((d0 >> 3) & 7);
        vt0[j] = ((d0 << 6) + row0) ^ (g0 << 3);
        int d1 = cc1 + j, g1 = (d1 & 7) ^ ((d1 >> 3) & 7);
        vt1[j] = ((d1 << 6) + row1) ^ (g1 << 3);
    }
    const u16* kc0 = k + (rowbase + row0) * 1024 + h64 + sl0;
    const u16* kc1 = k + (rowbase + row1) * 1024 + h64 + sl1;
    const u16* vc0 = v + (rowbase + row0) * 1024 + h64 + cc0;
    const u16* vc1 = v + (rowbase + row1) * 1024 + h64 + cc1;

    // Prologue: stage kt=0.
    async16(kc0, (char*)Ks + w * 1024);
    async16(kc1, (char*)Ks + 4096 + w * 1024);
    v8s vv0 = *(const v8s*)vc0;
    v8s vv1 = *(const v8s*)vc1;
    v8s vvn0 = vv0, vvn1 = vv1;
    int cur = 0;

    for (int kt = 0; kt < 16; kt++) {
        __syncthreads();   // prev PV done (Vt free); K(kt)/V(kt) drained
        const long koff = (long)(kt + 1) << 16;   // (kt+1)*64 rows * 1024
        if (kt < 15) {
            int nb = (cur ^ 1) * 8192;
            async16(kc0 + koff, (char*)Ks + nb + w * 1024);
            async16(kc1 + koff, (char*)Ks + nb + 4096 + w * 1024);
            vvn0 = *(const v8s*)(vc0 + koff);
            vvn1 = *(const v8s*)(vc1 + koff);
        }
        const u16* Kb = Ks + cur * 4096;

        v4f s[4];
#pragma unroll
        for (int nt = 0; nt < 4; nt++) {
            const u16* Kr = Kb + ((nt * 16 + lr) << 6);
            v8s b0 = *(const v8s*)(Kr + colk);
            v8s b1 = *(const v8s*)(Kr + (colk ^ 32));
            v4f t = zero4;
            t = __builtin_amdgcn_mfma_f32_16x16x32_bf16(aq0, b0, t, 0, 0, 0);
            t = __builtin_amdgcn_mfma_f32_16x16x32_bf16(aq1, b1, t, 0, 0, 0);
            s[nt] = t;
        }
#pragma unroll
        for (int r = 0; r < 4; r++) {
            float mx = fmaxf(fmaxf(s[0][r], s[1][r]), fmaxf(s[2][r], s[3][r]));
#pragma unroll
            for (int off = 1; off < 16; off <<= 1) mx = fmaxf(mx, __shfl_xor(mx, off));
            float mn = fmaxf(m_r[r], mx);
            float al = __expf(m_r[r] - mn);
            float rs = 0.f;
            int qrow = lq * 4 + r;
            int pbase = qrow << 6;
            int pswz = (qrow & 7) << 3;
#pragma unroll
            for (int nt = 0; nt < 4; nt++) {
                float pv = __expf(s[nt][r] - mn);
                rs += pv;
                Pp[pbase + ((nt * 16 + lr) ^ pswz)] = f2b(pv);
            }
#pragma unroll
            for (int off = 1; off < 16; off <<= 1) rs += __shfl_xor(rs, off);
            l_r[r] = l_r[r] * al + rs;
            m_r[r] = mn;
#pragma unroll
            for (int nt = 0; nt < 4; nt++) oacc[nt][r] *= al;
        }
        // V transpose stores (indices precomputed; data prefetched last iter).
#pragma unroll
        for (int j = 0; j < 8; j++) {
            Vt[vt0[j]] = (u16)vv0[j];
            Vt[vt1[j]] = (u16)vv1[j];
        }
        __syncthreads();   // Vt visible (also drains kt+1 prefetches)
        // Pw is wave-private; same-wave DS ops are in-order.
        const u16* Pr = Pp + (lr << 6);
        v8s pa0 = *(const v8s*)(Pr + colk);
        v8s pa1 = *(const v8s*)(Pr + (colk ^ 32));
#pragma unroll
        for (int nt = 0; nt < 4; nt++) {
            const u16* Vr = Vt + ((nt * 16 + lr) << 6);
            int gv = (ss ^ (2 * nt + (lr >> 3))) << 3;
            int colv = (lq << 3) ^ gv;
            v8s vb0 = *(const v8s*)(Vr + colv);
            v8s vb1 = *(const v8s*)(Vr + (colv ^ 32));
            oacc[nt] = __builtin_amdgcn_mfma_f32_16x16x32_bf16(pa0, vb0, oacc[nt], 0, 0, 0);
            oacc[nt] = __builtin_amdgcn_mfma_f32_16x16x32_bf16(pa1, vb1, oacc[nt], 0, 0, 0);
        }
        vv0 = vvn0; vv1 = vvn1;
        cur ^= 1;
    }
    bool bad = false;
#pragma unroll
    for (int r = 0; r < 4; r++) {
        float inv = 1.f / l_r[r];
#pragma unroll
        for (int nt = 0; nt < 4; nt++) {
            float val = oacc[nt][r] * inv;
            bad |= badf(val);
            ao[(rowbase + q0 + w * 16 + lq * 4 + r) * 1024 + h64 + nt * 16 + lr] = f2b(val);
        }
    }
    if (__ballot(bad) && l == 0) atomicMin(diag, stage);
}

// ---------------------------------------------------------------------------
// LayerNorm over E=1024 (fp32 out, final).
// ---------------------------------------------------------------------------
template <int F32OUT>
__global__ __launch_bounds__(256) void ln_k(const float* __restrict__ x,
                                            const u16* __restrict__ g, const u16* __restrict__ bt,
                                            u16* __restrict__ outb, float* __restrict__ outf,
                                            int stage, int* __restrict__ diag)
{
    __shared__ float red[8];
    int row = blockIdx.x, t = threadIdx.x, w = t >> 6;
    const float* xr = x + (long)row * 1024;
    float v[4], s = 0.f, sq = 0.f;
#pragma unroll
    for (int i = 0; i < 4; i++) { v[i] = xr[i * 256 + t]; s += v[i]; sq += v[i] * v[i]; }
#pragma unroll
    for (int off = 1; off < 64; off <<= 1) { s += __shfl_xor(s, off); sq += __shfl_xor(sq, off); }
    if ((t & 63) == 0) { red[w] = s; red[4 + w] = sq; }
    __syncthreads();
    float S = red[0] + red[1] + red[2] + red[3];
    float SQ = red[4] + red[5] + red[6] + red[7];
    float mean = S * (1.f / 1024.f);
    float var = fmaxf(SQ * (1.f / 1024.f) - mean * mean, 0.f);
    float rs = rsqrtf(var + 1e-5f);
    bool bad = false;
#pragma unroll
    for (int i = 0; i < 4; i++) {
        int e = i * 256 + t;
        float r = (v[i] - mean) * rs * b2f(g[e]) + b2f(bt[e]);
        bad |= badf(r);
        if (F32OUT) outf[(long)row * 1024 + e] = r;
        else outb[(long)row * 1024 + e] = f2b(r);
    }
    if (__ballot(bad) && (t & 63) == 0) atomicMin(diag, stage);
}

// Fused LN1+LN2: same row stats (same x), two affines, one pass.
__global__ __launch_bounds__(256) void ln12_k(const float* __restrict__ x,
                                              const u16* __restrict__ g1, const u16* __restrict__ b1,
                                              const u16* __restrict__ g2, const u16* __restrict__ b2,
                                              u16* __restrict__ out1, u16* __restrict__ out2,
                                              int stage, int* __restrict__ diag)
{
    __shared__ float red[8];
    int row = blockIdx.x, t = threadIdx.x, w = t >> 6;
    const float* xr = x + (long)row * 1024;
    float v[4], s = 0.f, sq = 0.f;
#pragma unroll
    for (int i = 0; i < 4; i++) { v[i] = xr[i * 256 + t]; s += v[i]; sq += v[i] * v[i]; }
#pragma unroll
    for (int off = 1; off < 64; off <<= 1) { s += __shfl_xor(s, off); sq += __shfl_xor(sq, off); }
    if ((t & 63) == 0) { red[w] = s; red[4 + w] = sq; }
    __syncthreads();
    float S = red[0] + red[1] + red[2] + red[3];
    float SQ = red[4] + red[5] + red[6] + red[7];
    float mean = S * (1.f / 1024.f);
    float var = fmaxf(SQ * (1.f / 1024.f) - mean * mean, 0.f);
    float rs = rsqrtf(var + 1e-5f);
    bool bad = false;
#pragma unroll
    for (int i = 0; i < 4; i++) {
        int e = i * 256 + t;
        float nv = (v[i] - mean) * rs;
        float r1 = nv * b2f(g1[e]) + b2f(b1[e]);
        float r2 = nv * b2f(g2[e]) + b2f(b2[e]);
        bad |= badf(r1) | badf(r2);
        out1[(long)row * 1024 + e] = f2b(r1);
        out2[(long)row * 1024 + e] = f2b(r2);
    }
    if (__ballot(bad) && (t & 63) == 0) atomicMin(diag, stage);
}

// ---------------------------------------------------------------------------
// rowfuse: tr = tra + trb (split-K partials).
__global__ __launch_bounds__(256) void rowfuse_k(
    const u16* __restrict__ cls, const u16* __restrict__ gate,
    const float* __restrict__ tra, const float* __restrict__ trb,
    const u16* __restrict__ ne, const u16* __restrict__ eew, const u16* __restrict__ eeb,
    const float* __restrict__ eta_p, float* __restrict__ xbuf, u16* __restrict__ x1b,
    int stage, int* __restrict__ diag)
{
    __shared__ float red[16];
    int row = blockIdx.x, t = threadIdx.x, w = t >> 6;
    long base = (long)row * 1024;
    float ifc[4];
#pragma unroll
    for (int i = 0; i < 4; i++) {
        int e = i * 256 + t;
        ifc[i] = b2f(cls[base + e]) + b2f(gate[base + e]) * (tra[base + e] + trb[base + e]);
    }
    float mx = fmaxf(fmaxf(ifc[0], ifc[1]), fmaxf(ifc[2], ifc[3]));
#pragma unroll
    for (int off = 1; off < 64; off <<= 1) mx = fmaxf(mx, __shfl_xor(mx, off));
    if ((t & 63) == 0) red[w] = mx;
    __syncthreads();
    float MX = fmaxf(fmaxf(red[0], red[1]), fmaxf(red[2], red[3]));
    float s1 = 0.f, s2 = 0.f, dot = 0.f;
#pragma unroll
    for (int i = 0; i < 4; i++) {
        int e = i * 256 + t;
        float ex = expf(ifc[i] - MX);
        s1 += ex; s2 += ex * ifc[i]; dot += ifc[i] * b2f(eew[e]);
    }
#pragma unroll
    for (int off = 1; off < 64; off <<= 1) {
        s1 += __shfl_xor(s1, off); s2 += __shfl_xor(s2, off); dot += __shfl_xor(dot, off);
    }
    if ((t & 63) == 0) { red[4 + w] = s1; red[8 + w] = s2; red[12 + w] = dot; }
    __syncthreads();
    float S1 = red[4] + red[5] + red[6] + red[7];
    float S2 = red[8] + red[9] + red[10] + red[11];
    float DT = red[12] + red[13] + red[14] + red[15];
    float logZ = MX + logf(S1);
    float ent = logZ - S2 / S1;
    float bal = 1.f / (1.f + expf(-(DT + b2f(eeb[0]))));
    float fac = eta_p[0] * bal / (ent + 1e-6f);
    bool bad = false;
#pragma unroll
    for (int i = 0; i < 4; i++) {
        int e = i * 256 + t;
        float rg = ifc[i] + fac * b2f(ne[base + e]);
        float x1 = xbuf[base + e] + rg;
        bad |= badf(x1);
        xbuf[base + e] = x1;
        x1b[base + e] = f2b(x1);
    }
    if (__ballot(bad) && (t & 63) == 0) atomicMin(diag, stage);
}

// softmax over sim partials: v = (pa + pb) * 0.03125/max(T,1e-8).
__global__ __launch_bounds__(256) void softmax_k(const float* __restrict__ pa, const float* __restrict__ pb,
                                                 const float* __restrict__ tp, u16* __restrict__ out,
                                                 int stage, int* __restrict__ diag)
{
    __shared__ float red[8];
    int row = blockIdx.x, t = threadIdx.x, w = t >> 6;
    long base = (long)row * 1024;
    float sc = 0.03125f / fmaxf(tp[0], 1e-8f);
    float v[4];
#pragma unroll
    for (int i = 0; i < 4; i++) v[i] = (pa[base + i * 256 + t] + pb[base + i * 256 + t]) * sc;
    float mx = fmaxf(fmaxf(v[0], v[1]), fmaxf(v[2], v[3]));
#pragma unroll
    for (int off = 1; off < 64; off <<= 1) mx = fmaxf(mx, __shfl_xor(mx, off));
    if ((t & 63) == 0) red[w] = mx;
    __syncthreads();
    float MX = fmaxf(fmaxf(red[0], red[1]), fmaxf(red[2], red[3]));
    float s = 0.f;
#pragma unroll
    for (int i = 0; i < 4; i++) { v[i] = expf(v[i] - MX); s += v[i]; }
#pragma unroll
    for (int off = 1; off < 64; off <<= 1) s += __shfl_xor(s, off);
    if ((t & 63) == 0) red[4 + w] = s;
    __syncthreads();
    float inv = 1.f / (red[4] + red[5] + red[6] + red[7]);
    bool bad = false;
#pragma unroll
    for (int i = 0; i < 4; i++) {
        float o = v[i] * inv;
        bad |= badf(o);
        out[base + i * 256 + t] = f2b(o);
    }
    if (__ballot(bad) && (t & 63) == 0) atomicMin(diag, stage);
}

// Fused dtype-convert + transpose: src [R,C] -> dst bf16 [C,R]. Check fused (stage 2).
__global__ void transpose_ft_k(const void* __restrict__ in, u16* __restrict__ out,
                               int R, int C, const int* __restrict__ flags, int idx,
                               int* __restrict__ diag)
{
    __shared__ u16 tile[32][33];
    int f = flags[idx];
    int x = blockIdx.x * 32 + threadIdx.x;
    int y0 = blockIdx.y * 32;
#pragma unroll
    for (int j = 0; j < 4; j++) {
        long src = (long)(y0 + threadIdx.y + j * 8) * C + x;
        tile[threadIdx.y + j * 8][threadIdx.x] =
            f ? f2b(((const float*)in)[src]) : ((const u16*)in)[src];
    }
    __syncthreads();
    int ox = y0 + threadIdx.x;
    int oy0 = blockIdx.x * 32;
    bool bad = false;
#pragma unroll
    for (int j = 0; j < 4; j++) {
        u16 u = tile[threadIdx.x][threadIdx.y + j * 8];
        bad |= ((u & 0x7FFF) >= 0x7F80);
        out[(long)(oy0 + threadIdx.y + j * 8) * R + ox] = u;
    }
    if (__ballot(bad) && ((threadIdx.y * 32 + threadIdx.x) & 63) == 0) atomicMin(diag, 2);
}

// Plain bf16 transpose (for quantum^T), batched via z.
__global__ void transpose_k(const u16* __restrict__ in, u16* __restrict__ out,
                            int R, int C, long sIn, long sOut)
{
    __shared__ u16 tile[32][33];
    int z = blockIdx.z;
    in += (long)z * sIn; out += (long)z * sOut;
    int x = blockIdx.x * 32 + threadIdx.x;
    int y0 = blockIdx.y * 32;
#pragma unroll
    for (int j = 0; j < 4; j++)
        tile[threadIdx.y + j * 8][threadIdx.x] = in[(long)(y0 + threadIdx.y + j * 8) * C + x];
    __syncthreads();
    int ox = y0 + threadIdx.x;
    int oy0 = blockIdx.x * 32;
#pragma unroll
    for (int j = 0; j < 4; j++)
        out[(long)(oy0 + threadIdx.y + j * 8) * R + ox] = tile[threadIdx.x][threadIdx.y + j * 8];
}

__global__ __launch_bounds__(256) void init_k(const void* __restrict__ xin, const int* __restrict__ flags,
                                              float* __restrict__ xbuf,
                                              float* __restrict__ ksf, u16* __restrict__ ksb,
                                              int* __restrict__ diag)
{
    int t = threadIdx.x;
    int f = flags[0];
    long base = (long)blockIdx.x * 1024;
    bool bad = false;
#pragma unroll
    for (int i = 0; i < 4; i++) {
        long idx = base + i * 256 + t;
        float xv = f ? ((const float*)xin)[idx] : b2f(((const u16*)xin)[idx]);
        bad |= badf(xv);
        xbuf[idx] = xv; ksf[idx] = xv; ksb[idx] = f2b(xv);
    }
    if (__ballot(bad) && (t & 63) == 0) atomicMin(diag, 1);
}

// ---------------------------------------------------------------------------
extern "C" void kernel_launch(void* const* d_in, const int* in_sizes, int n_in,
                              void* d_out, int out_size, void* d_ws, size_t ws_size,
                              hipStream_t stream)
{
    const size_t MB = 1u << 20;
    float* outf = (float*)d_out;
    if (ws_size < 192 * MB) {
        int code = (int)(ws_size >> 25); if (code > 9) code = 9;
        small_k<<<1, 64, 0, stream>>>(outf, code);
        return;
    }
    const u16* s_refg = (const u16*)d_in[11];
    const u16* s_temp = (const u16*)d_in[18];
    const u16* s_eta  = (const u16*)d_in[23];
    const u16* s_obsg = (const u16*)d_in[36];

    InArr IA;
    for (int i = 0; i < 37; i++) { IA.p[i] = d_in[i]; IA.n[i] = (i < n_in) ? in_sizes[i] : 0; }

    char* ws = (char*)d_ws;
    // Weight slots: srv merged [2048,1024] at 0MB, qk merged [2048,1024] at 4MB.
    u16* srT  = (u16*)(ws + 0 * MB);    // sr rows 0-1023
    u16* vT   = (u16*)(ws + 2 * MB);    // v rows 1024-2047 (contiguous with srT)
    u16* qT   = (u16*)(ws + 4 * MB);    // q rows 0-1023
    u16* kT   = (u16*)(ws + 6 * MB);    // k rows 1024-2047 (contiguous with qT)
    u16* oT   = (u16*)(ws + 8 * MB);
    u16* cT   = (u16*)(ws + 10 * MB);
    u16* qpT  = (u16*)(ws + 12 * MB);
    u16* kpT  = (u16*)(ws + 14 * MB);
    u16* obsT = (u16*)(ws + 16 * MB);
    u16* igT  = (u16*)(ws + 18 * MB);   // [1024,2048]
    u16* f1T  = (u16*)(ws + 22 * MB);   // [4096,1024]
    u16* f2T  = (u16*)(ws + 30 * MB);   // [1024,4096]
    float* scal = (float*)(ws + 38 * MB);
    int* diag  = (int*)(ws + 38 * MB + 64);
    int* flags = (int*)(ws + 38 * MB + 128);
    int* cnt   = (int*)(ws + 38 * MB + 512);
    u16* BIA   = (u16*)(ws + 38 * MB + 8192);
    // Bias layout: sr|v contiguous (merged srv), q|k contiguous (merged qk).
    u16* c_bsr = BIA + 0*1024,  *c_bv = BIA + 1*1024;
    u16* c_bq  = BIA + 2*1024,  *c_bk = BIA + 3*1024;
    u16* c_bo  = BIA + 4*1024,  *c_bc = BIA + 5*1024;
    u16* c_bqp = BIA + 6*1024,  *c_big = BIA + 7*1024, *c_bkp = BIA + 8*1024;
    u16* c_bobs= BIA + 9*1024,  *c_bf2 = BIA + 10*1024;
    u16* c_g1  = BIA + 11*1024, *c_be1 = BIA + 12*1024;
    u16* c_g2  = BIA + 13*1024, *c_be2 = BIA + 14*1024;
    u16* c_g3  = BIA + 15*1024, *c_be3 = BIA + 16*1024;
    u16* c_eew = BIA + 17*1024, *c_eeb = BIA + 18*1024;
    u16* c_bf1 = BIA + 19*1024;
    float* xbuf = (float*)(ws + 40 * MB);
    float* ksf  = (float*)(ws + 56 * MB);
    u16* ksb    = (u16*)(ws + 72 * MB);
    u16* xn     = (u16*)(ws + 80 * MB);
    u16* xn2    = (u16*)(ws + 88 * MB);
    u16* xr     = (u16*)(ws + 96 * MB);
    u16* qb     = (u16*)(ws + 104 * MB);
    u16* kb     = (u16*)(ws + 112 * MB);
    u16* vb     = (u16*)(ws + 120 * MB);
    u16* aob    = (u16*)(ws + 128 * MB);
    u16* quant  = (u16*)(ws + 136 * MB);
    u16* hb     = (u16*)(ws + 144 * MB);  // 32 MB (144-176); dead after f2c
    u16* clsb   = (u16*)(ws + 176 * MB);
    u16* neb    = (u16*)(ws + 184 * MB);
    // Serially reused fp32 partial slots (16MB each at 144/160MB):
    //  ig -> igc; sim -> softmax; trf -> rowfuse.
    // f2 partials at 104/120MB (qb..aob dead at f2 time).
    float* f2pa = (float*)(ws + 104 * MB);
    float* f2pb = (float*)(ws + 120 * MB);
    float* ppa  = (float*)(ws + 144 * MB);
    float* ppb  = (float*)(ws + 160 * MB);
    u16* quantT = xn;
    u16* cpb = qb;  u16* qpb = kb;  u16* gateb = vb;  u16* attw = aob;  u16* x1b = xr;

    const long BS1 = 1024L * 1024L;
    const int KBIG = 1 << 30;
    dim3 tb(32, 8), blk(256), gblk(512);
    GJ2 J0 = {nullptr, nullptr, nullptr, nullptr};

    auto G = [&](int epi, int gx, int gy, int gz,
                 const u16* A, int lda, long sA, const u16* A2, int ksp,
                 const u16* Bt, int ldb, long sB, const u16* bias,
                 u16* obf, float* of32, int ldc, long sC, int K,
                 const float* scp, const u16* aux, float* xa, float* kf, u16* kb2, float* kso,
                 GJ2 J2, int stg) {
        dim3 grid(gx, gy, gz);
        switch (epi) {
            case 0: gemm_bt<0><<<grid, gblk, 0, stream>>>(A, lda, sA, A2, ksp, Bt, ldb, sB, bias, obf, of32, ldc, sC, K, scp, aux, xa, kf, kb2, kso, J2, stg, diag); break;
            case 2: gemm_bt<2><<<grid, gblk, 0, stream>>>(A, lda, sA, A2, ksp, Bt, ldb, sB, bias, obf, of32, ldc, sC, K, scp, aux, xa, kf, kb2, kso, J2, stg, diag); break;
            case 5: gemm_bt<5><<<grid, gblk, 0, stream>>>(A, lda, sA, A2, ksp, Bt, ldb, sB, bias, obf, of32, ldc, sC, K, scp, aux, xa, kf, kb2, kso, J2, stg, diag); break;
            case 6: gemm_bt<6><<<grid, gblk, 0, stream>>>(A, lda, sA, A2, ksp, Bt, ldb, sB, bias, obf, of32, ldc, sC, K, scp, aux, xa, kf, kb2, kso, J2, stg, diag); break;
            case 7: gemm_bt<7><<<grid, gblk, 0, stream>>>(A, lda, sA, A2, ksp, Bt, ldb, sB, bias, obf, of32, ldc, sC, K, scp, aux, xa, kf, kb2, kso, J2, stg, diag); break;
            case 8: gemm_bt<8><<<grid, gblk, 0, stream>>>(A, lda, sA, A2, ksp, Bt, ldb, sB, bias, obf, of32, ldc, sC, K, scp, aux, xa, kf, kb2, kso, J2, stg, diag); break;
        }
    };

    // ---- setup ----
    reset_k<<<1, 256, 0, stream>>>(diag, cnt);
    classify_k<<<dim3(8, 37), blk, 0, stream>>>(IA, cnt);
    finalize_k<<<1, 64, 0, stream>>>(IA, cnt, flags);
    decode_scalars_k<<<1, 64, 0, stream>>>(s_refg, s_temp, s_eta, s_obsg, scal);
    // Bias/1D jobs. Order: sr,v | q,k contiguous for the merged GEMMs.
    BJobs BJ = {
        {2, 8, 4, 6, 10, 13, 15, 17, 20, 35, 27, 28, 29, 30, 31, 32, 33, 21, 22, 25},
        {0, 1, 2, 3, 4, 5, 6, 7, 8, 9, 10, 11, 12, 13, 14, 15, 16, 17, 18, 19},
        {1024,1024,1024,1024,1024,1024,1024,1024,1024,1024,1024,1024,1024,1024,1024,1024,1024,1024,1,4096}
    };
    cvt1d_k<<<dim3(4, 20), blk, 0, stream>>>(IA, BJ, flags, BIA);
    struct WT { int idx; u16* dst; long n; int R, C, gx, gy; };
    WT wts[12] = {
        {1, srT, 1048576, 1024, 1024, 32, 32},  {7, vT, 1048576, 1024, 1024, 32, 32},
        {3, qT, 1048576, 1024, 1024, 32, 32},   {5, kT, 1048576, 1024, 1024, 32, 32},
        {9, oT, 1048576, 1024, 1024, 32, 32},   {12, cT, 1048576, 1024, 1024, 32, 32},
        {14, qpT, 1048576, 1024, 1024, 32, 32}, {19, kpT, 1048576, 1024, 1024, 32, 32},
        {34, obsT, 1048576, 1024, 1024, 32, 32},
        {16, igT, 2097152, 2048, 1024, 32, 64},
        {24, f1T, 4194304, 1024, 4096, 128, 32},
        {26, f2T, 4194304, 4096, 1024, 32, 128},
    };
    for (int i = 0; i < 12; i++) {
        transpose_ft_k<<<dim3(wts[i].gx, wts[i].gy, 1), tb, 0, stream>>>(
            d_in[wts[i].idx], wts[i].dst, wts[i].R, wts[i].C, flags, wts[i].idx, diag);
    }
    init_k<<<4096, blk, 0, stream>>>(d_in[0], flags, xbuf, ksf, ksb, diag);
    chk_scal_k<<<1, 64, 0, stream>>>(scal, diag);

    for (int it = 0; it < 3; it++) {
        int sb = 4 + it * 20;
        // fused ln1+ln2 (same stats): xn + xn2 in one xbuf pass.
        ln12_k<<<4096, blk, 0, stream>>>(xbuf, c_g1, c_be1, c_g2, c_be2, xn, xn2, sb + 0, diag);
        // merged sr|v: N=2048, A=xn. col<1024 -> xr (SR residual), else -> vb.
        GJ2 Jsrv = {nullptr, nullptr, nullptr, vb};
        G(6, 16, 32, 1, xn, 1024, 0, nullptr, KBIG, srT, 1024, 0, c_bsr, xr, nullptr, 1024, 0, 1024, scal + 0, xn, nullptr, nullptr, nullptr, nullptr, Jsrv, sb + 1);
        // merged q|k: N=2048, A=xr. col<1024 -> qb (pre-scaled 0.125), else -> kb.
        GJ2 Jqk = {nullptr, nullptr, nullptr, kb};
        G(7, 16, 32, 1, xr, 1024, 0, nullptr, KBIG, qT, 1024, 0, c_bq, qb, nullptr, 1024, 0, 1024, nullptr, nullptr, nullptr, nullptr, nullptr, nullptr, Jqk, sb + 2);
        // flash (non-split, direct bf16 out).
        flash_k<<<dim3(16, 64), blk, 0, stream>>>(qb, kb, vb, aob, sb + 5, diag);
        // dual (o, kp): z0 A=aob->quant, z1 A=ksb->neb.
        GJ2 Jokp = {ksb, kpT, c_bkp, neb};
        G(0, 8, 32, 2, aob, 1024, 0, nullptr, KBIG, oT, 1024, 0, c_bo, quant, nullptr, 1024, 0, 1024, nullptr, nullptr, nullptr, nullptr, nullptr, nullptr, Jokp, sb + 6);
        transpose_k<<<dim3(32, 32, 4), tb, 0, stream>>>(quant, quantT, 1024, 1024, BS1, BS1);
        G(2, 32, 32, 1, xn2, 1024, 0, nullptr, KBIG, f1T, 1024, 0, c_bf1, hb, nullptr, 4096, 0, 1024, nullptr, nullptr, nullptr, nullptr, nullptr, nullptr, J0, sb + 8);
        // f2 split-K=2: fp32 partials into f2pa/f2pb (dead qb..aob region).
        G(8, 8, 32, 2, hb, 4096, 2048, nullptr, KBIG, f2T, 4096, 2048, nullptr, nullptr, f2pa, 1024, 4194304, 2048, nullptr, nullptr, nullptr, nullptr, nullptr, nullptr, J0, sb + 9);
        f2c_k<<<4096, blk, 0, stream>>>(f2pa, f2pb, c_bf2, clsb, sb + 9, diag);
        // dual (c, qp): z0 A=clsb->cpb, z1 A=quant->qpb.
        GJ2 Jcqp = {quant, qpT, c_bqp, qpb};
        G(0, 8, 32, 2, clsb, 1024, 0, nullptr, KBIG, cT, 1024, 0, c_bc, cpb, nullptr, 1024, 0, 1024, nullptr, nullptr, nullptr, nullptr, nullptr, nullptr, Jcqp, sb + 10);
        // ig split-K=2 via dual-job: z0 = cpb x igT[:, :1024] -> ppa,
        // z1 = qpb x igT[:, 1024:] -> ppb. Combine adds bias + sigmoid.
        GJ2 Jig = {qpb, igT + 1024, nullptr, (u16*)ppb};
        G(8, 8, 32, 2, cpb, 1024, 0, nullptr, KBIG, igT, 2048, 0, nullptr, nullptr, ppa, 1024, 0, 1024, nullptr, nullptr, nullptr, nullptr, nullptr, nullptr, Jig, sb + 12);
        igc_k<<<4096, blk, 0, stream>>>(ppa, ppb, c_big, gateb, sb + 12, diag);
        // sim split-K=2, batched z=4: grid (8,8,8). Halves of K=1024 at +512.
        GJ2 Jsim = {cpb + 512, qpb + 512, nullptr, (u16*)ppb};
        G(8, 8, 8, 8, cpb, 1024, BS1, nullptr, KBIG, qpb, 1024, BS1, nullptr, nullptr, ppa, 1024, BS1, 512, nullptr, nullptr, nullptr, nullptr, nullptr, nullptr, Jsim, sb + 14);
        softmax_k<<<4096, blk, 0, stream>>>(ppa, ppb, scal + 1, attw, sb + 15, diag);
        // trf split-K=2, batched z=4 (sim partials consumed by softmax above).
        GJ2 Jtrf = {attw + 512, quantT + 512, nullptr, (u16*)ppb};
        G(8, 8, 8, 8, attw, 1024, BS1, nullptr, KBIG, quantT, 1024, BS1, nullptr, nullptr, ppa, 1024, BS1, 512, nullptr, nullptr, nullptr, nullptr, nullptr, nullptr, Jtrf, sb + 16);
        rowfuse_k<<<4096, blk, 0, stream>>>(clsb, gateb, ppa, ppb, neb, c_eew, c_eeb, scal + 2, xbuf, x1b, sb + 17, diag);
        float* kso = (it == 2) ? (outf + 4194304) : nullptr;
        G(5, 8, 32, 1, x1b, 1024, 0, nullptr, KBIG, obsT, 1024, 0, c_bobs, nullptr, nullptr, 1024, 0, 1024, scal + 3, nullptr, xbuf, ksf, ksb, kso, J0, sb + 18);
    }
    ln_k<1><<<4096, blk, 0, stream>>>(xbuf, c_g3, c_be3, nullptr, outf, 70, diag);
    fin32_k<<<1024, blk, 0, stream>>>(outf, 2097152, diag);
}